// Round 2
// baseline (1030.047 us; speedup 1.0000x reference)
//
#include <hip/hip_runtime.h>
#include <hip/hip_bf16.h>

#define BB 1024
#define NSLOT 32
#define DD 1024
#define HH 4096

typedef __bf16 bfx8 __attribute__((ext_vector_type(8)));
typedef float f32x4 __attribute__((ext_vector_type(4)));

__device__ __forceinline__ unsigned short f2bfu(float f) {
  union { float f; unsigned u; } v; v.f = f;
  unsigned r = v.u + 0x7fffu + ((v.u >> 16) & 1u);
  return (unsigned short)(r >> 16);
}
__device__ __forceinline__ float bfu2f(unsigned short u) {
  union { unsigned u; float f; } v; v.u = ((unsigned)u) << 16; return v.f;
}
__device__ __forceinline__ float gelu_f(float x) {
  return 0.5f * x * (1.0f + erff(x * 0.70710678118654752f));
}

// fast gate math: v_exp_f32 + v_rcp_f32 (~1 ulp each; error << bf16 rounding).
// Validated in round 1 (absmax identical to libm version).
__device__ __forceinline__ float sigm_fast(float x) {
  // 1 / (1 + 2^(-x*log2e)); x->+inf => 1, x->-inf => 0 (exp2 overflow -> rcp(inf)=0)
  return __builtin_amdgcn_rcpf(1.0f + __builtin_amdgcn_exp2f(-1.4426950408889634f * x));
}
__device__ __forceinline__ float tanh_fast(float x) {
  // tanh(x) = 1 - 2/(1 + 2^(2x*log2e)); saturates correctly at +/-1
  float t = __builtin_amdgcn_exp2f(2.8853900817779268f * x);
  return 1.0f - 2.0f * __builtin_amdgcn_rcpf(1.0f + t);
}

// async global->LDS, 16B per lane; LDS dest = wave-uniform base + lane*16
__device__ __forceinline__ void async16(const unsigned short* g, unsigned short* l) {
  __builtin_amdgcn_global_load_lds(
      (const __attribute__((address_space(1))) unsigned int*)g,
      (__attribute__((address_space(3))) unsigned int*)l, 16, 0, 0);
}

// ---------------- conversion / transpose kernels ----------------

__global__ __launch_bounds__(256) void cvt_x_ctx(const float* __restrict__ x,
                                                 unsigned short* __restrict__ ctx) {
  int i = blockIdx.x * 256 + threadIdx.x;
  int b = i >> 8;
  int c4 = (i & 255) * 4;
  float4 v = ((const float4*)(x + (size_t)b * DD))[i & 255];
  ushort4 o; o.x = f2bfu(v.x); o.y = f2bfu(v.y); o.z = f2bfu(v.z); o.w = f2bfu(v.w);
  *(ushort4*)&ctx[(size_t)b * (2 * DD) + c4] = o;
}

__global__ __launch_bounds__(256) void cvt4(const float* __restrict__ in,
                                            unsigned short* __restrict__ out, int n4) {
  int i = blockIdx.x * 256 + threadIdx.x;
  if (i >= n4) return;
  float4 v = ((const float4*)in)[i];
  ushort4 o; o.x = f2bfu(v.x); o.y = f2bfu(v.y); o.z = f2bfu(v.z); o.w = f2bfu(v.w);
  ((ushort4*)out)[i] = o;
}

__global__ __launch_bounds__(256) void slot_mean_k(const unsigned short* __restrict__ Sb,
                                                   unsigned short* __restrict__ ctx) {
  int i = blockIdx.x * 256 + threadIdx.x;
  int b = i >> 10, d = i & 1023;
  const unsigned short* p = Sb + (size_t)b * NSLOT * DD + d;
  float s = 0.f;
  #pragma unroll
  for (int sl = 0; sl < NSLOT; sl++) s += bfu2f(p[sl * DD]);
  ctx[(size_t)b * (2 * DD) + DD + d] = f2bfu(s * (1.0f / NSLOT));
}

__global__ __launch_bounds__(256) void transp(const float* __restrict__ in,
                                              unsigned short* __restrict__ out,
                                              int R, int C) {
  __shared__ float t[32][33];
  int tx = threadIdx.x & 31, ty = threadIdx.x >> 5;
  int c0 = blockIdx.x * 32, r0 = blockIdx.y * 32;
  #pragma unroll
  for (int i = 0; i < 4; i++) {
    int r = r0 + ty * 4 + i;
    t[ty * 4 + i][tx] = in[(size_t)r * C + c0 + tx];
  }
  __syncthreads();
  #pragma unroll
  for (int i = 0; i < 4; i++) {
    int c = c0 + ty * 4 + i;
    out[(size_t)c * R + r0 + tx] = f2bfu(t[tx][ty * 4 + i]);
  }
}

// ---------------- generic NT bf16 MFMA GEMM ----------------
template <int EPI>
__global__ __launch_bounds__(256) void gemm_nt(
    const unsigned short* __restrict__ A, int lda,
    const unsigned short* __restrict__ Bt, int ldb, int K,
    const float* __restrict__ bias,
    const float* __restrict__ add, int ldadd,
    float* __restrict__ outF, unsigned short* __restrict__ outB, int ldout) {
  __shared__ __align__(16) unsigned short lA[128 * 40];
  __shared__ __align__(16) unsigned short lB[64 * 40];
  const int tid = threadIdx.x;
  const int wave = tid >> 6, lane = tid & 63;
  const int q = lane >> 4, l15 = lane & 15;
  const int row0 = blockIdx.y * 128;
  const int col0 = blockIdx.x * 64;
  const int ar = tid >> 2;
  const int ac = (tid & 3) * 8;

  f32x4 acc[2][4];
  #pragma unroll
  for (int m = 0; m < 2; m++)
    #pragma unroll
    for (int n = 0; n < 4; n++) acc[m][n] = (f32x4){0.f, 0.f, 0.f, 0.f};

  for (int k0 = 0; k0 < K; k0 += 32) {
    *(uint4*)&lA[ar * 40 + ac] = *(const uint4*)&A[(size_t)(row0 + ar) * lda + k0 + ac];
    *(uint4*)&lA[(ar + 64) * 40 + ac] = *(const uint4*)&A[(size_t)(row0 + ar + 64) * lda + k0 + ac];
    *(uint4*)&lB[ar * 40 + ac] = *(const uint4*)&Bt[(size_t)(col0 + ar) * ldb + k0 + ac];
    __syncthreads();
    bfx8 af[2], bf[4];
    #pragma unroll
    for (int m = 0; m < 2; m++)
      af[m] = *(const bfx8*)&lA[(wave * 32 + m * 16 + l15) * 40 + q * 8];
    #pragma unroll
    for (int n = 0; n < 4; n++)
      bf[n] = *(const bfx8*)&lB[(n * 16 + l15) * 40 + q * 8];
    #pragma unroll
    for (int m = 0; m < 2; m++)
      #pragma unroll
      for (int n = 0; n < 4; n++)
        acc[m][n] = __builtin_amdgcn_mfma_f32_16x16x32_bf16(af[m], bf[n], acc[m][n], 0, 0, 0);
    __syncthreads();
  }

  #pragma unroll
  for (int m = 0; m < 2; m++) {
    #pragma unroll
    for (int n = 0; n < 4; n++) {
      int gr0 = row0 + wave * 32 + m * 16 + q * 4;
      int gc = col0 + n * 16 + l15;
      #pragma unroll
      for (int i = 0; i < 4; i++) {
        int gr = gr0 + i;
        float v = acc[m][n][i];
        if (EPI == 0) {
          outF[(size_t)gr * ldout + gc] = v;
        } else if (EPI == 1) {
          float t = gelu_f(v + bias[gc]);
          outB[(size_t)gr * ldout + gc] = f2bfu(t);
        } else {
          outF[(size_t)gr * ldout + gc] = v + bias[gc] + add[(size_t)gr * ldadd + gc];
        }
      }
    }
  }
}

// ---------------- fused GRU GEMM (m97-style) + gates + slot-context ----------------
// A = Sb [B*NS, D] bf16 ; Whht [3D, D] bf16 ; grid (D/64, B*NS/128), 256 thr.
// Tile: 128 rows x 64 cols x 3 gates, BK=64 (2 halves of 32).
// K-loop: REVERTED to the round-0 single-buffer 2-barrier structure (measured
// 394 us; the explicit dbuf variant regressed to 499 us — full vmcnt drain at
// __syncthreads defeats source-level prefetch, per m99/m100/m131-m141).
// Staging via global_load_lds w=16; LDS rows 64B, XOR chunk swizzle c^((r>>1)&3).
// Epilogue: GRU gates with FAST exp2/rcp transcendentals (validated round 1,
// absmax unchanged) + S_new (fp32) + fused alpha-weighted slot-context (bf16).
__global__ __launch_bounds__(256) void gru_gemm(
    const unsigned short* __restrict__ Sb, const unsigned short* __restrict__ Whht,
    const float* __restrict__ alpha, const float* __restrict__ xw,
    const float* __restrict__ b_ih, const float* __restrict__ b_hh,
    const float* __restrict__ Sf, float* __restrict__ Snew,
    unsigned short* __restrict__ sc_b) {
  __shared__ __align__(16) unsigned short lA[2][128 * 32];   // 16 KB
  __shared__ __align__(16) unsigned short lB[2][192 * 32];   // 24 KB
  const int tid = threadIdx.x;
  const int wave = tid >> 6, lane = tid & 63;
  const int wr = wave >> 1, wc = wave & 1;
  const int q = lane >> 4, l15 = lane & 15;
  const int row0 = blockIdx.y * 128;
  const int col0 = blockIdx.x * 64;
  const int halfA = 128 * 32, halfB = 192 * 32;

  // ---- staging descriptors (loop-invariant; advance by 64 elems/iter) ----
  const int lr = lane >> 2, scn = lane & 3;
  const unsigned short* aSrc[2];
  unsigned short* aDst[2];
  #pragma unroll
  for (int j = 0; j < 2; j++) {
    int R0 = (2 * wave + j) * 16;
    int r = R0 + lr;
    int c = scn ^ ((r >> 1) & 3);
    aSrc[j] = Sb + (size_t)(row0 + r) * DD + c * 8;
    aDst[j] = &lA[0][R0 * 32];
  }
  const unsigned short* bSrc[3];
  unsigned short* bDst[3];
  #pragma unroll
  for (int j = 0; j < 3; j++) {
    int R0 = (3 * wave + j) * 16;
    int r = R0 + lr;
    int g = r >> 6, cr = r & 63;
    int c = scn ^ ((r >> 1) & 3);
    bSrc[j] = Whht + ((size_t)g * DD + col0 + cr) * DD + c * 8;
    bDst[j] = &lB[0][R0 * 32];
  }

  // ---- fragment read offsets (loop-invariant, swizzled) ----
  int offA[4];
  #pragma unroll
  for (int m = 0; m < 4; m++) {
    int r = wr * 64 + m * 16 + l15;
    offA[m] = r * 32 + (q ^ ((r >> 1) & 3)) * 8;
  }
  int offB[3][2];
  #pragma unroll
  for (int g = 0; g < 3; g++)
    #pragma unroll
    for (int n = 0; n < 2; n++) {
      int r = g * 64 + wc * 32 + n * 16 + l15;
      offB[g][n] = r * 32 + (q ^ ((r >> 1) & 3)) * 8;
    }

  f32x4 acc[3][4][2];
  #pragma unroll
  for (int g = 0; g < 3; g++)
    #pragma unroll
    for (int m = 0; m < 4; m++)
      #pragma unroll
      for (int n = 0; n < 2; n++) acc[g][m][n] = (f32x4){0.f, 0.f, 0.f, 0.f};

  // ---- K loop: 16 iters of BK=64 ----
  for (int it = 0; it < 16; it++) {
    #pragma unroll
    for (int j = 0; j < 2; j++) {
      async16(aSrc[j], aDst[j]);
      async16(aSrc[j] + 32, aDst[j] + halfA);
      aSrc[j] += 64;
    }
    #pragma unroll
    for (int j = 0; j < 3; j++) {
      async16(bSrc[j], bDst[j]);
      async16(bSrc[j] + 32, bDst[j] + halfB);
      bSrc[j] += 64;
    }
    __syncthreads();   // drains vmcnt -> staged data visible
    #pragma unroll
    for (int h = 0; h < 2; h++) {
      bfx8 af[4];
      #pragma unroll
      for (int m = 0; m < 4; m++) af[m] = *(const bfx8*)&lA[h][offA[m]];
      #pragma unroll
      for (int g = 0; g < 3; g++) {
        bfx8 bf0 = *(const bfx8*)&lB[h][offB[g][0]];
        bfx8 bf1 = *(const bfx8*)&lB[h][offB[g][1]];
        #pragma unroll
        for (int m = 0; m < 4; m++) {
          acc[g][m][0] = __builtin_amdgcn_mfma_f32_16x16x32_bf16(af[m], bf0, acc[g][m][0], 0, 0, 0);
          acc[g][m][1] = __builtin_amdgcn_mfma_f32_16x16x32_bf16(af[m], bf1, acc[g][m][1], 0, 0, 0);
        }
      }
    }
    __syncthreads();   // protect LDS from next iter's staging
  }

  // ---- epilogue: gates (fast math) + S_new + fused slot-context ----
  float scp[2][2] = {{0.f, 0.f}, {0.f, 0.f}};
  #pragma unroll
  for (int m = 0; m < 4; m++) {
    #pragma unroll
    for (int i = 0; i < 4; i++) {
      int gr = row0 + wr * 64 + m * 16 + q * 4 + i;
      float a = alpha[gr];
      const float* xwr = xw + (size_t)(gr >> 5) * (3 * DD);
      const float* sfr = Sf + (size_t)gr * DD;
      float* orow = Snew + (size_t)gr * DD;
      #pragma unroll
      for (int n = 0; n < 2; n++) {
        int gc = col0 + wc * 32 + n * 16 + l15;
        float ghr = acc[0][m][n][i] + b_hh[gc];
        float ghz = acc[1][m][n][i] + b_hh[gc + DD];
        float ghn = acc[2][m][n][i] + b_hh[gc + 2 * DD];
        float r = sigm_fast(a * xwr[gc] + b_ih[gc] + ghr);
        float z = sigm_fast(a * xwr[gc + DD] + b_ih[gc + DD] + ghz);
        float nn = tanh_fast(a * xwr[gc + 2 * DD] + b_ih[gc + 2 * DD] + r * ghn);
        float sv = (1.0f - z) * nn + z * sfr[gc];
        orow[gc] = sv;
        scp[m >> 1][n] += a * sv;
      }
    }
  }
  #pragma unroll
  for (int bh = 0; bh < 2; bh++)
    #pragma unroll
    for (int n = 0; n < 2; n++) {
      float v = scp[bh][n];
      v += __shfl_xor(v, 16);
      v += __shfl_xor(v, 32);
      if (q == 0) {
        int batch = (row0 >> 5) + wr * 2 + bh;
        int gc = col0 + wc * 32 + n * 16 + l15;
        sc_b[(size_t)batch * DD + gc] = f2bfu(v);
      }
    }
}

// ---------------- routing logits + softmax ----------------
__global__ __launch_bounds__(256) void route_softmax(
    const unsigned short* __restrict__ h_r, const float* __restrict__ w_r2,
    const float* __restrict__ b_r2, float* __restrict__ alpha_out) {
  int b = blockIdx.x;
  int n = threadIdx.x & 31, c = threadIdx.x >> 5;
  __shared__ float part[8][32];
  __shared__ float logits[32];
  const unsigned short* hr = h_r + (size_t)b * DD;
  float s = 0.f;
  for (int i = 0; i < 128; i++) {
    int k = c * 128 + i;
    s += bfu2f(hr[k]) * w_r2[k * NSLOT + n];
  }
  part[c][n] = s;
  __syncthreads();
  if (threadIdx.x < 32) {
    float t = b_r2[n];
    #pragma unroll
    for (int cc = 0; cc < 8; cc++) t += part[cc][n];
    logits[n] = t;
  }
  __syncthreads();
  if (threadIdx.x < 32) {
    float mx = -1e30f;
    #pragma unroll
    for (int j = 0; j < 32; j++) mx = fmaxf(mx, logits[j]);
    float den = 0.f;
    #pragma unroll
    for (int j = 0; j < 32; j++) den += expf(logits[j] - mx);
    alpha_out[(size_t)b * NSLOT + n] = expf(logits[n] - mx) / den;
  }
}

// ---------------- layernorm ----------------
template <int OUT_BF>
__global__ __launch_bounds__(256) void ln_k(const float* __restrict__ in,
                                            const float* __restrict__ gw,
                                            const float* __restrict__ bw,
                                            float* __restrict__ outF,
                                            unsigned short* __restrict__ outB) {
  int b = blockIdx.x;
  int tid = threadIdx.x;
  float4 v = ((const float4*)(in + (size_t)b * DD))[tid];
  float s = v.x + v.y + v.z + v.w;
  float s2 = v.x * v.x + v.y * v.y + v.z * v.z + v.w * v.w;
  #pragma unroll
  for (int o = 32; o > 0; o >>= 1) { s += __shfl_down(s, o); s2 += __shfl_down(s2, o); }
  __shared__ float as1[4], as2[4];
  int wave = tid >> 6, lane = tid & 63;
  if (lane == 0) { as1[wave] = s; as2[wave] = s2; }
  __syncthreads();
  float t1 = as1[0] + as1[1] + as1[2] + as1[3];
  float t2 = as2[0] + as2[1] + as2[2] + as2[3];
  float mu = t1 * (1.0f / DD);
  float var = t2 * (1.0f / DD) - mu * mu;
  float rstd = rsqrtf(var + 1e-5f);
  int d = tid * 4;
  float o0 = (v.x - mu) * rstd * gw[d] + bw[d];
  float o1 = (v.y - mu) * rstd * gw[d + 1] + bw[d + 1];
  float o2 = (v.z - mu) * rstd * gw[d + 2] + bw[d + 2];
  float o3 = (v.w - mu) * rstd * gw[d + 3] + bw[d + 3];
  if (OUT_BF) {
    ushort4 o; o.x = f2bfu(o0); o.y = f2bfu(o1); o.z = f2bfu(o2); o.w = f2bfu(o3);
    *(ushort4*)&outB[(size_t)b * DD + d] = o;
  } else {
    float4 o; o.x = o0; o.y = o1; o.z = o2; o.w = o3;
    *(float4*)&outF[(size_t)b * DD + d] = o;
  }
}

// ---------------- launch ----------------
extern "C" void kernel_launch(void* const* d_in, const int* in_sizes, int n_in,
                              void* d_out, int out_size, void* d_ws, size_t ws_size,
                              hipStream_t stream) {
  const float* x      = (const float*)d_in[0];
  const float* S      = (const float*)d_in[1];
  const float* w_r1   = (const float*)d_in[2];
  const float* b_r1   = (const float*)d_in[3];
  const float* w_r2   = (const float*)d_in[4];
  const float* b_r2   = (const float*)d_in[5];
  const float* w_ih   = (const float*)d_in[6];
  const float* w_hh   = (const float*)d_in[7];
  const float* b_ih   = (const float*)d_in[8];
  const float* b_hh   = (const float*)d_in[9];
  const float* w_proj = (const float*)d_in[10];
  const float* b_proj = (const float*)d_in[11];
  const float* ln1_g  = (const float*)d_in[12];
  const float* ln1_b  = (const float*)d_in[13];
  const float* w_f1   = (const float*)d_in[14];
  const float* b_f1   = (const float*)d_in[15];
  const float* w_f2   = (const float*)d_in[16];
  const float* b_f2   = (const float*)d_in[17];
  const float* ln2_g  = (const float*)d_in[18];
  const float* ln2_b  = (const float*)d_in[19];

  float* out_x = (float*)d_out;
  float* out_S = out_x + (size_t)BB * DD;
  float* out_a = out_S + (size_t)BB * NSLOT * DD;

  char* ws = (char*)d_ws;
  unsigned short* ctx    = (unsigned short*)(ws + 0);             // 4 MB [B][2D]
  unsigned short* w_r1t  = (unsigned short*)(ws + 4194304);       // 4 MB [D][2D]
  unsigned short* w_iht  = (unsigned short*)(ws + 8388608);       // 6 MB [3D][D]
  unsigned short* w_hht  = (unsigned short*)(ws + 14680064);      // 6 MB [3D][D]
  unsigned short* w_projt= (unsigned short*)(ws + 20971520);      // 2 MB [D][D]
  unsigned short* w_f1t  = (unsigned short*)(ws + 23068672);      // 8 MB [H][D]
  unsigned short* w_f2t  = (unsigned short*)(ws + 31457280);      // 8 MB [D][H]
  unsigned short* h_r    = (unsigned short*)(ws + 39845888);      // 2 MB [B][D]
  float*          xw     = (float*)(ws + 41943040);               // 12 MB [B][3D]
  unsigned short* Sb     = (unsigned short*)(ws + 54525952);      // 64 MB [B*NS][D]
  // aliases (lifetimes don't overlap originals):
  unsigned short* sc_b   = (unsigned short*)(ws + 0);             // reuse ctx (dead after xw GEMM)
  float*          x_mid  = (float*)(ws + 41943040);               // reuse xw (dead after gru)
  unsigned short* h_ln   = (unsigned short*)(ws + 46137344);      // xw + 4MB
  float*          pre2   = (float*)(ws + 48234496);               // xw + 6MB
  unsigned short* ff1    = (unsigned short*)(ws + 54525952);      // reuse Sb (dead after gru)

  dim3 blk(256);
  // --- prep: conversions + weight transposes ---
  cvt_x_ctx<<<1024, blk, 0, stream>>>(x, ctx);
  cvt4<<<32768, blk, 0, stream>>>(S, Sb, (BB * NSLOT * DD) / 4);
  slot_mean_k<<<4096, blk, 0, stream>>>(Sb, ctx);
  transp<<<dim3(32, 64), blk, 0, stream>>>(w_r1, w_r1t, 2 * DD, DD);
  transp<<<dim3(96, 32), blk, 0, stream>>>(w_ih, w_iht, DD, 3 * DD);
  transp<<<dim3(96, 32), blk, 0, stream>>>(w_hh, w_hht, DD, 3 * DD);
  transp<<<dim3(32, 32), blk, 0, stream>>>(w_proj, w_projt, DD, DD);
  transp<<<dim3(128, 32), blk, 0, stream>>>(w_f1, w_f1t, DD, HH);
  transp<<<dim3(32, 128), blk, 0, stream>>>(w_f2, w_f2t, HH, DD);

  // --- routing ---
  gemm_nt<1><<<dim3(16, 8), blk, 0, stream>>>(ctx, 2 * DD, w_r1t, 2 * DD, 2 * DD,
                                              b_r1, nullptr, 0, nullptr, h_r, DD);
  route_softmax<<<1024, blk, 0, stream>>>(h_r, w_r2, b_r2, out_a);

  // --- xw = x @ w_ih (rank-1 trick: gi = alpha * xw) ---
  gemm_nt<0><<<dim3(48, 8), blk, 0, stream>>>(ctx, 2 * DD, w_iht, DD, DD,
                                              nullptr, nullptr, 0, xw, nullptr, 3 * DD);

  // --- fused GRU: gh GEMM + gates + S_new + slot-context ---
  gru_gemm<<<dim3(16, 256), blk, 0, stream>>>(Sb, w_hht, out_a, xw, b_ih, b_hh, S,
                                              out_S, sc_b);

  // --- proj + residual ---
  gemm_nt<2><<<dim3(16, 8), blk, 0, stream>>>(sc_b, DD, w_projt, DD, DD,
                                              b_proj, x, DD, x_mid, nullptr, DD);

  // --- LN1 -> FFN -> LN2 ---
  ln_k<1><<<1024, blk, 0, stream>>>(x_mid, ln1_g, ln1_b, nullptr, h_ln);
  gemm_nt<1><<<dim3(64, 8), blk, 0, stream>>>(h_ln, DD, w_f1t, DD, DD,
                                              b_f1, nullptr, 0, nullptr, ff1, HH);
  gemm_nt<2><<<dim3(16, 8), blk, 0, stream>>>(ff1, HH, w_f2t, HH, HH,
                                              b_f2, x_mid, DD, pre2, nullptr, DD);
  ln_k<0><<<1024, blk, 0, stream>>>(pre2, ln2_g, ln2_b, out_x, nullptr);
}

// Round 3
// 920.470 us; speedup vs baseline: 1.1190x; 1.1190x over previous
//
#include <hip/hip_runtime.h>
#include <hip/hip_bf16.h>

#define BB 1024
#define NSLOT 32
#define DD 1024
#define HH 4096

typedef __bf16 bfx8 __attribute__((ext_vector_type(8)));
typedef float f32x4 __attribute__((ext_vector_type(4)));

__device__ __forceinline__ unsigned short f2bfu(float f) {
  union { float f; unsigned u; } v; v.f = f;
  unsigned r = v.u + 0x7fffu + ((v.u >> 16) & 1u);
  return (unsigned short)(r >> 16);
}
__device__ __forceinline__ float bfu2f(unsigned short u) {
  union { unsigned u; float f; } v; v.u = ((unsigned)u) << 16; return v.f;
}
__device__ __forceinline__ float gelu_f(float x) {
  return 0.5f * x * (1.0f + erff(x * 0.70710678118654752f));
}

// fast gate math: v_exp_f32 + v_rcp_f32 (~1 ulp each; error << bf16 rounding).
// Validated in rounds 1-2 (absmax identical to libm version).
__device__ __forceinline__ float sigm_fast(float x) {
  return __builtin_amdgcn_rcpf(1.0f + __builtin_amdgcn_exp2f(-1.4426950408889634f * x));
}
__device__ __forceinline__ float tanh_fast(float x) {
  float t = __builtin_amdgcn_exp2f(2.8853900817779268f * x);
  return 1.0f - 2.0f * __builtin_amdgcn_rcpf(1.0f + t);
}

// async global->LDS, 16B per lane; LDS dest = wave-uniform base + lane*16
__device__ __forceinline__ void async16(const unsigned short* g, unsigned short* l) {
  __builtin_amdgcn_global_load_lds(
      (const __attribute__((address_space(1))) unsigned int*)g,
      (__attribute__((address_space(3))) unsigned int*)l, 16, 0, 0);
}

// ---------------- conversion / transpose kernels ----------------

__global__ __launch_bounds__(256) void cvt_x_ctx(const float* __restrict__ x,
                                                 unsigned short* __restrict__ ctx) {
  int i = blockIdx.x * 256 + threadIdx.x;
  int b = i >> 8;
  int c4 = (i & 255) * 4;
  float4 v = ((const float4*)(x + (size_t)b * DD))[i & 255];
  ushort4 o; o.x = f2bfu(v.x); o.y = f2bfu(v.y); o.z = f2bfu(v.z); o.w = f2bfu(v.w);
  *(ushort4*)&ctx[(size_t)b * (2 * DD) + c4] = o;
}

__global__ __launch_bounds__(256) void cvt4(const float* __restrict__ in,
                                            unsigned short* __restrict__ out, int n4) {
  int i = blockIdx.x * 256 + threadIdx.x;
  if (i >= n4) return;
  float4 v = ((const float4*)in)[i];
  ushort4 o; o.x = f2bfu(v.x); o.y = f2bfu(v.y); o.z = f2bfu(v.z); o.w = f2bfu(v.w);
  ((ushort4*)out)[i] = o;
}

__global__ __launch_bounds__(256) void slot_mean_k(const unsigned short* __restrict__ Sb,
                                                   unsigned short* __restrict__ ctx) {
  int i = blockIdx.x * 256 + threadIdx.x;
  int b = i >> 10, d = i & 1023;
  const unsigned short* p = Sb + (size_t)b * NSLOT * DD + d;
  float s = 0.f;
  #pragma unroll
  for (int sl = 0; sl < NSLOT; sl++) s += bfu2f(p[sl * DD]);
  ctx[(size_t)b * (2 * DD) + DD + d] = f2bfu(s * (1.0f / NSLOT));
}

__global__ __launch_bounds__(256) void transp(const float* __restrict__ in,
                                              unsigned short* __restrict__ out,
                                              int R, int C) {
  __shared__ float t[32][33];
  int tx = threadIdx.x & 31, ty = threadIdx.x >> 5;
  int c0 = blockIdx.x * 32, r0 = blockIdx.y * 32;
  #pragma unroll
  for (int i = 0; i < 4; i++) {
    int r = r0 + ty * 4 + i;
    t[ty * 4 + i][tx] = in[(size_t)r * C + c0 + tx];
  }
  __syncthreads();
  #pragma unroll
  for (int i = 0; i < 4; i++) {
    int c = c0 + ty * 4 + i;
    out[(size_t)c * R + r0 + tx] = f2bfu(t[tx][ty * 4 + i]);
  }
}

// ---------------- NT bf16 MFMA GEMM, gru-style global_load_lds staging ----------
// REWRITTEN this round on the verified gru_gemm structure: 128x64 tile, BK=64
// (2 halves of 32), single-buffer 2-barrier loop, async16 staging with
// 64B LDS rows + XOR chunk swizzle c^((r>>1)&3) (both-sides involution).
// Requires: rows%128==0, cols%64==0, K%64==0, lda/ldb >= K (all call sites ok).
template <int EPI>
__global__ __launch_bounds__(256) void gemm_nt(
    const unsigned short* __restrict__ A, int lda,
    const unsigned short* __restrict__ Bt, int ldb, int K,
    const float* __restrict__ bias,
    const float* __restrict__ add, int ldadd,
    float* __restrict__ outF, unsigned short* __restrict__ outB, int ldout) {
  __shared__ __align__(16) unsigned short lA[2][128 * 32];   // 16 KB [half]
  __shared__ __align__(16) unsigned short lB[2][64 * 32];    // 8 KB  [half]
  const int tid = threadIdx.x;
  const int wave = tid >> 6, lane = tid & 63;
  const int wr = wave >> 1, wc = wave & 1;
  const int q = lane >> 4, l15 = lane & 15;
  const int row0 = blockIdx.y * 128;
  const int col0 = blockIdx.x * 64;
  const int halfA = 128 * 32, halfB = 64 * 32;

  // staging descriptors: A = 4 waves x 2 chunks of 16 rows; B = 4 waves x 1 chunk
  const int lr = lane >> 2, scn = lane & 3;
  const unsigned short* aSrc[2];
  unsigned short* aDst[2];
  #pragma unroll
  for (int j = 0; j < 2; j++) {
    int R0 = (2 * wave + j) * 16;
    int r = R0 + lr;
    int c = scn ^ ((r >> 1) & 3);
    aSrc[j] = A + (size_t)(row0 + r) * lda + c * 8;
    aDst[j] = &lA[0][R0 * 32];
  }
  const unsigned short* bSrc;
  unsigned short* bDst;
  {
    int R0 = wave * 16;
    int r = R0 + lr;
    int c = scn ^ ((r >> 1) & 3);
    bSrc = Bt + (size_t)(col0 + r) * ldb + c * 8;
    bDst = &lB[0][R0 * 32];
  }

  // fragment read offsets (swizzled)
  int offA[4];
  #pragma unroll
  for (int m = 0; m < 4; m++) {
    int r = wr * 64 + m * 16 + l15;
    offA[m] = r * 32 + (q ^ ((r >> 1) & 3)) * 8;
  }
  int offB[2];
  #pragma unroll
  for (int n = 0; n < 2; n++) {
    int r = wc * 32 + n * 16 + l15;
    offB[n] = r * 32 + (q ^ ((r >> 1) & 3)) * 8;
  }

  f32x4 acc[4][2];
  #pragma unroll
  for (int m = 0; m < 4; m++)
    #pragma unroll
    for (int n = 0; n < 2; n++) acc[m][n] = (f32x4){0.f, 0.f, 0.f, 0.f};

  const int iters = K >> 6;
  for (int it = 0; it < iters; it++) {
    #pragma unroll
    for (int j = 0; j < 2; j++) {
      async16(aSrc[j], aDst[j]);
      async16(aSrc[j] + 32, aDst[j] + halfA);
      aSrc[j] += 64;
    }
    async16(bSrc, bDst);
    async16(bSrc + 32, bDst + halfB);
    bSrc += 64;
    __syncthreads();   // drains vmcnt -> staged data visible
    #pragma unroll
    for (int h = 0; h < 2; h++) {
      bfx8 af[4];
      #pragma unroll
      for (int m = 0; m < 4; m++) af[m] = *(const bfx8*)&lA[h][offA[m]];
      bfx8 bf0 = *(const bfx8*)&lB[h][offB[0]];
      bfx8 bf1 = *(const bfx8*)&lB[h][offB[1]];
      #pragma unroll
      for (int m = 0; m < 4; m++) {
        acc[m][0] = __builtin_amdgcn_mfma_f32_16x16x32_bf16(af[m], bf0, acc[m][0], 0, 0, 0);
        acc[m][1] = __builtin_amdgcn_mfma_f32_16x16x32_bf16(af[m], bf1, acc[m][1], 0, 0, 0);
      }
    }
    __syncthreads();   // protect LDS from next iter's staging
  }

  #pragma unroll
  for (int m = 0; m < 4; m++) {
    #pragma unroll
    for (int n = 0; n < 2; n++) {
      int gr0 = row0 + wr * 64 + m * 16 + q * 4;
      int gc = col0 + wc * 32 + n * 16 + l15;
      #pragma unroll
      for (int i = 0; i < 4; i++) {
        int gr = gr0 + i;
        float v = acc[m][n][i];
        if (EPI == 0) {
          outF[(size_t)gr * ldout + gc] = v;
        } else if (EPI == 1) {
          float t = gelu_f(v + bias[gc]);
          outB[(size_t)gr * ldout + gc] = f2bfu(t);
        } else {
          outF[(size_t)gr * ldout + gc] = v + bias[gc] + add[(size_t)gr * ldadd + gc];
        }
      }
    }
  }
}

// ---------------- fused GRU GEMM + gates + slot-context ----------------
// Same K-loop as round 0 (measured 394 us). Fast-math epilogue kept.
// THIS ROUND: __launch_bounds__(256, 2) pins regalloc to 2 blocks/CU
// (2 waves/SIMD) — round 2's fast-math epilogue pushed VGPR 108->144,
// total unified regs past the cliff, halving occupancy (22.6 -> 11.8%).
// K-loop needs ~140 regs so the cap cannot spill the main loop.
__global__ __launch_bounds__(256, 2) void gru_gemm(
    const unsigned short* __restrict__ Sb, const unsigned short* __restrict__ Whht,
    const float* __restrict__ alpha, const float* __restrict__ xw,
    const float* __restrict__ b_ih, const float* __restrict__ b_hh,
    const float* __restrict__ Sf, float* __restrict__ Snew,
    unsigned short* __restrict__ sc_b) {
  __shared__ __align__(16) unsigned short lA[2][128 * 32];   // 16 KB
  __shared__ __align__(16) unsigned short lB[2][192 * 32];   // 24 KB
  const int tid = threadIdx.x;
  const int wave = tid >> 6, lane = tid & 63;
  const int wr = wave >> 1, wc = wave & 1;
  const int q = lane >> 4, l15 = lane & 15;
  const int row0 = blockIdx.y * 128;
  const int col0 = blockIdx.x * 64;
  const int halfA = 128 * 32, halfB = 192 * 32;

  const int lr = lane >> 2, scn = lane & 3;
  const unsigned short* aSrc[2];
  unsigned short* aDst[2];
  #pragma unroll
  for (int j = 0; j < 2; j++) {
    int R0 = (2 * wave + j) * 16;
    int r = R0 + lr;
    int c = scn ^ ((r >> 1) & 3);
    aSrc[j] = Sb + (size_t)(row0 + r) * DD + c * 8;
    aDst[j] = &lA[0][R0 * 32];
  }
  const unsigned short* bSrc[3];
  unsigned short* bDst[3];
  #pragma unroll
  for (int j = 0; j < 3; j++) {
    int R0 = (3 * wave + j) * 16;
    int r = R0 + lr;
    int g = r >> 6, cr = r & 63;
    int c = scn ^ ((r >> 1) & 3);
    bSrc[j] = Whht + ((size_t)g * DD + col0 + cr) * DD + c * 8;
    bDst[j] = &lB[0][R0 * 32];
  }

  int offA[4];
  #pragma unroll
  for (int m = 0; m < 4; m++) {
    int r = wr * 64 + m * 16 + l15;
    offA[m] = r * 32 + (q ^ ((r >> 1) & 3)) * 8;
  }
  int offB[3][2];
  #pragma unroll
  for (int g = 0; g < 3; g++)
    #pragma unroll
    for (int n = 0; n < 2; n++) {
      int r = g * 64 + wc * 32 + n * 16 + l15;
      offB[g][n] = r * 32 + (q ^ ((r >> 1) & 3)) * 8;
    }

  f32x4 acc[3][4][2];
  #pragma unroll
  for (int g = 0; g < 3; g++)
    #pragma unroll
    for (int m = 0; m < 4; m++)
      #pragma unroll
      for (int n = 0; n < 2; n++) acc[g][m][n] = (f32x4){0.f, 0.f, 0.f, 0.f};

  for (int it = 0; it < 16; it++) {
    #pragma unroll
    for (int j = 0; j < 2; j++) {
      async16(aSrc[j], aDst[j]);
      async16(aSrc[j] + 32, aDst[j] + halfA);
      aSrc[j] += 64;
    }
    #pragma unroll
    for (int j = 0; j < 3; j++) {
      async16(bSrc[j], bDst[j]);
      async16(bSrc[j] + 32, bDst[j] + halfB);
      bSrc[j] += 64;
    }
    __syncthreads();
    #pragma unroll
    for (int h = 0; h < 2; h++) {
      bfx8 af[4];
      #pragma unroll
      for (int m = 0; m < 4; m++) af[m] = *(const bfx8*)&lA[h][offA[m]];
      #pragma unroll
      for (int g = 0; g < 3; g++) {
        bfx8 bf0 = *(const bfx8*)&lB[h][offB[g][0]];
        bfx8 bf1 = *(const bfx8*)&lB[h][offB[g][1]];
        #pragma unroll
        for (int m = 0; m < 4; m++) {
          acc[g][m][0] = __builtin_amdgcn_mfma_f32_16x16x32_bf16(af[m], bf0, acc[g][m][0], 0, 0, 0);
          acc[g][m][1] = __builtin_amdgcn_mfma_f32_16x16x32_bf16(af[m], bf1, acc[g][m][1], 0, 0, 0);
        }
      }
    }
    __syncthreads();
  }

  // ---- epilogue: gates (fast math) + S_new + fused slot-context ----
  float scp[2][2] = {{0.f, 0.f}, {0.f, 0.f}};
  #pragma unroll
  for (int m = 0; m < 4; m++) {
    #pragma unroll
    for (int i = 0; i < 4; i++) {
      int gr = row0 + wr * 64 + m * 16 + q * 4 + i;
      float a = alpha[gr];
      const float* xwr = xw + (size_t)(gr >> 5) * (3 * DD);
      const float* sfr = Sf + (size_t)gr * DD;
      float* orow = Snew + (size_t)gr * DD;
      #pragma unroll
      for (int n = 0; n < 2; n++) {
        int gc = col0 + wc * 32 + n * 16 + l15;
        float ghr = acc[0][m][n][i] + b_hh[gc];
        float ghz = acc[1][m][n][i] + b_hh[gc + DD];
        float ghn = acc[2][m][n][i] + b_hh[gc + 2 * DD];
        float r = sigm_fast(a * xwr[gc] + b_ih[gc] + ghr);
        float z = sigm_fast(a * xwr[gc + DD] + b_ih[gc + DD] + ghz);
        float nn = tanh_fast(a * xwr[gc + 2 * DD] + b_ih[gc + 2 * DD] + r * ghn);
        float sv = (1.0f - z) * nn + z * sfr[gc];
        orow[gc] = sv;
        scp[m >> 1][n] += a * sv;
      }
    }
  }
  #pragma unroll
  for (int bh = 0; bh < 2; bh++)
    #pragma unroll
    for (int n = 0; n < 2; n++) {
      float v = scp[bh][n];
      v += __shfl_xor(v, 16);
      v += __shfl_xor(v, 32);
      if (q == 0) {
        int batch = (row0 >> 5) + wr * 2 + bh;
        int gc = col0 + wc * 32 + n * 16 + l15;
        sc_b[(size_t)batch * DD + gc] = f2bfu(v);
      }
    }
}

// ---------------- routing logits + softmax ----------------
__global__ __launch_bounds__(256) void route_softmax(
    const unsigned short* __restrict__ h_r, const float* __restrict__ w_r2,
    const float* __restrict__ b_r2, float* __restrict__ alpha_out) {
  int b = blockIdx.x;
  int n = threadIdx.x & 31, c = threadIdx.x >> 5;
  __shared__ float part[8][32];
  __shared__ float logits[32];
  const unsigned short* hr = h_r + (size_t)b * DD;
  float s = 0.f;
  for (int i = 0; i < 128; i++) {
    int k = c * 128 + i;
    s += bfu2f(hr[k]) * w_r2[k * NSLOT + n];
  }
  part[c][n] = s;
  __syncthreads();
  if (threadIdx.x < 32) {
    float t = b_r2[n];
    #pragma unroll
    for (int cc = 0; cc < 8; cc++) t += part[cc][n];
    logits[n] = t;
  }
  __syncthreads();
  if (threadIdx.x < 32) {
    float mx = -1e30f;
    #pragma unroll
    for (int j = 0; j < 32; j++) mx = fmaxf(mx, logits[j]);
    float den = 0.f;
    #pragma unroll
    for (int j = 0; j < 32; j++) den += expf(logits[j] - mx);
    alpha_out[(size_t)b * NSLOT + n] = expf(logits[n] - mx) / den;
  }
}

// ---------------- layernorm ----------------
template <int OUT_BF>
__global__ __launch_bounds__(256) void ln_k(const float* __restrict__ in,
                                            const float* __restrict__ gw,
                                            const float* __restrict__ bw,
                                            float* __restrict__ outF,
                                            unsigned short* __restrict__ outB) {
  int b = blockIdx.x;
  int tid = threadIdx.x;
  float4 v = ((const float4*)(in + (size_t)b * DD))[tid];
  float s = v.x + v.y + v.z + v.w;
  float s2 = v.x * v.x + v.y * v.y + v.z * v.z + v.w * v.w;
  #pragma unroll
  for (int o = 32; o > 0; o >>= 1) { s += __shfl_down(s, o); s2 += __shfl_down(s2, o); }
  __shared__ float as1[4], as2[4];
  int wave = tid >> 6, lane = tid & 63;
  if (lane == 0) { as1[wave] = s; as2[wave] = s2; }
  __syncthreads();
  float t1 = as1[0] + as1[1] + as1[2] + as1[3];
  float t2 = as2[0] + as2[1] + as2[2] + as2[3];
  float mu = t1 * (1.0f / DD);
  float var = t2 * (1.0f / DD) - mu * mu;
  float rstd = rsqrtf(var + 1e-5f);
  int d = tid * 4;
  float o0 = (v.x - mu) * rstd * gw[d] + bw[d];
  float o1 = (v.y - mu) * rstd * gw[d + 1] + bw[d + 1];
  float o2 = (v.z - mu) * rstd * gw[d + 2] + bw[d + 2];
  float o3 = (v.w - mu) * rstd * gw[d + 3] + bw[d + 3];
  if (OUT_BF) {
    ushort4 o; o.x = f2bfu(o0); o.y = f2bfu(o1); o.z = f2bfu(o2); o.w = f2bfu(o3);
    *(ushort4*)&outB[(size_t)b * DD + d] = o;
  } else {
    float4 o; o.x = o0; o.y = o1; o.z = o2; o.w = o3;
    *(float4*)&outF[(size_t)b * DD + d] = o;
  }
}

// ---------------- launch ----------------
extern "C" void kernel_launch(void* const* d_in, const int* in_sizes, int n_in,
                              void* d_out, int out_size, void* d_ws, size_t ws_size,
                              hipStream_t stream) {
  const float* x      = (const float*)d_in[0];
  const float* S      = (const float*)d_in[1];
  const float* w_r1   = (const float*)d_in[2];
  const float* b_r1   = (const float*)d_in[3];
  const float* w_r2   = (const float*)d_in[4];
  const float* b_r2   = (const float*)d_in[5];
  const float* w_ih   = (const float*)d_in[6];
  const float* w_hh   = (const float*)d_in[7];
  const float* b_ih   = (const float*)d_in[8];
  const float* b_hh   = (const float*)d_in[9];
  const float* w_proj = (const float*)d_in[10];
  const float* b_proj = (const float*)d_in[11];
  const float* ln1_g  = (const float*)d_in[12];
  const float* ln1_b  = (const float*)d_in[13];
  const float* w_f1   = (const float*)d_in[14];
  const float* b_f1   = (const float*)d_in[15];
  const float* w_f2   = (const float*)d_in[16];
  const float* b_f2   = (const float*)d_in[17];
  const float* ln2_g  = (const float*)d_in[18];
  const float* ln2_b  = (const float*)d_in[19];

  float* out_x = (float*)d_out;
  float* out_S = out_x + (size_t)BB * DD;
  float* out_a = out_S + (size_t)BB * NSLOT * DD;

  char* ws = (char*)d_ws;
  unsigned short* ctx    = (unsigned short*)(ws + 0);             // 4 MB [B][2D]
  unsigned short* w_r1t  = (unsigned short*)(ws + 4194304);       // 4 MB [D][2D]
  unsigned short* w_iht  = (unsigned short*)(ws + 8388608);       // 6 MB [3D][D]
  unsigned short* w_hht  = (unsigned short*)(ws + 14680064);      // 6 MB [3D][D]
  unsigned short* w_projt= (unsigned short*)(ws + 20971520);      // 2 MB [D][D]
  unsigned short* w_f1t  = (unsigned short*)(ws + 23068672);      // 8 MB [H][D]
  unsigned short* w_f2t  = (unsigned short*)(ws + 31457280);      // 8 MB [D][H]
  unsigned short* h_r    = (unsigned short*)(ws + 39845888);      // 2 MB [B][D]
  float*          xw     = (float*)(ws + 41943040);               // 12 MB [B][3D]
  unsigned short* Sb     = (unsigned short*)(ws + 54525952);      // 64 MB [B*NS][D]
  // aliases (lifetimes don't overlap originals):
  unsigned short* sc_b   = (unsigned short*)(ws + 0);             // reuse ctx (dead after xw GEMM)
  float*          x_mid  = (float*)(ws + 41943040);               // reuse xw (dead after gru)
  unsigned short* h_ln   = (unsigned short*)(ws + 46137344);      // xw + 4MB
  float*          pre2   = (float*)(ws + 48234496);               // xw + 6MB
  unsigned short* ff1    = (unsigned short*)(ws + 54525952);      // reuse Sb (dead after gru)

  dim3 blk(256);
  // --- prep: conversions + weight transposes ---
  cvt_x_ctx<<<1024, blk, 0, stream>>>(x, ctx);
  cvt4<<<32768, blk, 0, stream>>>(S, Sb, (BB * NSLOT * DD) / 4);
  slot_mean_k<<<4096, blk, 0, stream>>>(Sb, ctx);
  transp<<<dim3(32, 64), blk, 0, stream>>>(w_r1, w_r1t, 2 * DD, DD);
  transp<<<dim3(96, 32), blk, 0, stream>>>(w_ih, w_iht, DD, 3 * DD);
  transp<<<dim3(96, 32), blk, 0, stream>>>(w_hh, w_hht, DD, 3 * DD);
  transp<<<dim3(32, 32), blk, 0, stream>>>(w_proj, w_projt, DD, DD);
  transp<<<dim3(128, 32), blk, 0, stream>>>(w_f1, w_f1t, DD, HH);
  transp<<<dim3(32, 128), blk, 0, stream>>>(w_f2, w_f2t, HH, DD);

  // --- routing ---
  gemm_nt<1><<<dim3(16, 8), blk, 0, stream>>>(ctx, 2 * DD, w_r1t, 2 * DD, 2 * DD,
                                              b_r1, nullptr, 0, nullptr, h_r, DD);
  route_softmax<<<1024, blk, 0, stream>>>(h_r, w_r2, b_r2, out_a);

  // --- xw = x @ w_ih (rank-1 trick: gi = alpha * xw) ---
  gemm_nt<0><<<dim3(48, 8), blk, 0, stream>>>(ctx, 2 * DD, w_iht, DD, DD,
                                              nullptr, nullptr, 0, xw, nullptr, 3 * DD);

  // --- fused GRU: gh GEMM + gates + S_new + slot-context ---
  gru_gemm<<<dim3(16, 256), blk, 0, stream>>>(Sb, w_hht, out_a, xw, b_ih, b_hh, S,
                                              out_S, sc_b);

  // --- proj + residual ---
  gemm_nt<2><<<dim3(16, 8), blk, 0, stream>>>(sc_b, DD, w_projt, DD, DD,
                                              b_proj, x, DD, x_mid, nullptr, DD);

  // --- LN1 -> FFN -> LN2 ---
  ln_k<1><<<1024, blk, 0, stream>>>(x_mid, ln1_g, ln1_b, nullptr, h_ln);
  gemm_nt<1><<<dim3(64, 8), blk, 0, stream>>>(h_ln, DD, w_f1t, DD, DD,
                                              b_f1, nullptr, 0, nullptr, ff1, HH);
  gemm_nt<2><<<dim3(16, 8), blk, 0, stream>>>(ff1, HH, w_f2t, HH, HH,
                                              b_f2, x_mid, DD, pre2, nullptr, DD);
  ln_k<0><<<1024, blk, 0, stream>>>(pre2, ln2_g, ln2_b, out_x, nullptr);
}

// Round 4
// 759.479 us; speedup vs baseline: 1.3563x; 1.2120x over previous
//
#include <hip/hip_runtime.h>
#include <hip/hip_bf16.h>

#define BB 1024
#define NSLOT 32
#define DD 1024
#define HH 4096

typedef __bf16 bfx8 __attribute__((ext_vector_type(8)));
typedef float f32x4 __attribute__((ext_vector_type(4)));

__device__ __forceinline__ unsigned short f2bfu(float f) {
  union { float f; unsigned u; } v; v.f = f;
  unsigned r = v.u + 0x7fffu + ((v.u >> 16) & 1u);
  return (unsigned short)(r >> 16);
}
__device__ __forceinline__ float bfu2f(unsigned short u) {
  union { unsigned u; float f; } v; v.u = ((unsigned)u) << 16; return v.f;
}
__device__ __forceinline__ float gelu_f(float x) {
  return 0.5f * x * (1.0f + erff(x * 0.70710678118654752f));
}

// fast gate math: v_exp_f32 + v_rcp_f32 (~1 ulp each; error << bf16 rounding).
// Validated rounds 1-3 (absmax identical to libm version).
__device__ __forceinline__ float sigm_fast(float x) {
  return __builtin_amdgcn_rcpf(1.0f + __builtin_amdgcn_exp2f(-1.4426950408889634f * x));
}
__device__ __forceinline__ float tanh_fast(float x) {
  float t = __builtin_amdgcn_exp2f(2.8853900817779268f * x);
  return 1.0f - 2.0f * __builtin_amdgcn_rcpf(1.0f + t);
}

// async global->LDS, 16B per lane; LDS dest = wave-uniform base + lane*16
__device__ __forceinline__ void async16(const unsigned short* g, unsigned short* l) {
  __builtin_amdgcn_global_load_lds(
      (const __attribute__((address_space(1))) unsigned int*)g,
      (__attribute__((address_space(3))) unsigned int*)l, 16, 0, 0);
}

// ---------------- conversion / transpose kernels ----------------

__global__ __launch_bounds__(256) void cvt_x_ctx(const float* __restrict__ x,
                                                 unsigned short* __restrict__ ctx) {
  int i = blockIdx.x * 256 + threadIdx.x;
  int b = i >> 8;
  int c4 = (i & 255) * 4;
  float4 v = ((const float4*)(x + (size_t)b * DD))[i & 255];
  ushort4 o; o.x = f2bfu(v.x); o.y = f2bfu(v.y); o.z = f2bfu(v.z); o.w = f2bfu(v.w);
  *(ushort4*)&ctx[(size_t)b * (2 * DD) + c4] = o;
}

__global__ __launch_bounds__(256) void cvt4(const float* __restrict__ in,
                                            unsigned short* __restrict__ out, int n4) {
  int i = blockIdx.x * 256 + threadIdx.x;
  if (i >= n4) return;
  float4 v = ((const float4*)in)[i];
  ushort4 o; o.x = f2bfu(v.x); o.y = f2bfu(v.y); o.z = f2bfu(v.z); o.w = f2bfu(v.w);
  ((ushort4*)out)[i] = o;
}

__global__ __launch_bounds__(256) void slot_mean_k(const unsigned short* __restrict__ Sb,
                                                   unsigned short* __restrict__ ctx) {
  int i = blockIdx.x * 256 + threadIdx.x;
  int b = i >> 10, d = i & 1023;
  const unsigned short* p = Sb + (size_t)b * NSLOT * DD + d;
  float s = 0.f;
  #pragma unroll
  for (int sl = 0; sl < NSLOT; sl++) s += bfu2f(p[sl * DD]);
  ctx[(size_t)b * (2 * DD) + DD + d] = f2bfu(s * (1.0f / NSLOT));
}

__global__ __launch_bounds__(256) void transp(const float* __restrict__ in,
                                              unsigned short* __restrict__ out,
                                              int R, int C) {
  __shared__ float t[32][33];
  int tx = threadIdx.x & 31, ty = threadIdx.x >> 5;
  int c0 = blockIdx.x * 32, r0 = blockIdx.y * 32;
  #pragma unroll
  for (int i = 0; i < 4; i++) {
    int r = r0 + ty * 4 + i;
    t[ty * 4 + i][tx] = in[(size_t)r * C + c0 + tx];
  }
  __syncthreads();
  #pragma unroll
  for (int i = 0; i < 4; i++) {
    int c = c0 + ty * 4 + i;
    out[(size_t)c * R + r0 + tx] = f2bfu(t[tx][ty * 4 + i]);
  }
}

// ---------------- NT bf16 MFMA GEMM, gru-style global_load_lds staging ----------
// (unchanged this round for clean A/B on gru_gemm)
template <int EPI>
__global__ __launch_bounds__(256) void gemm_nt(
    const unsigned short* __restrict__ A, int lda,
    const unsigned short* __restrict__ Bt, int ldb, int K,
    const float* __restrict__ bias,
    const float* __restrict__ add, int ldadd,
    float* __restrict__ outF, unsigned short* __restrict__ outB, int ldout) {
  __shared__ __align__(16) unsigned short lA[2][128 * 32];   // 16 KB [half]
  __shared__ __align__(16) unsigned short lB[2][64 * 32];    // 8 KB  [half]
  const int tid = threadIdx.x;
  const int wave = tid >> 6, lane = tid & 63;
  const int wr = wave >> 1, wc = wave & 1;
  const int q = lane >> 4, l15 = lane & 15;
  const int row0 = blockIdx.y * 128;
  const int col0 = blockIdx.x * 64;
  const int halfA = 128 * 32, halfB = 64 * 32;

  const int lr = lane >> 2, scn = lane & 3;
  const unsigned short* aSrc[2];
  unsigned short* aDst[2];
  #pragma unroll
  for (int j = 0; j < 2; j++) {
    int R0 = (2 * wave + j) * 16;
    int r = R0 + lr;
    int c = scn ^ ((r >> 1) & 3);
    aSrc[j] = A + (size_t)(row0 + r) * lda + c * 8;
    aDst[j] = &lA[0][R0 * 32];
  }
  const unsigned short* bSrc;
  unsigned short* bDst;
  {
    int R0 = wave * 16;
    int r = R0 + lr;
    int c = scn ^ ((r >> 1) & 3);
    bSrc = Bt + (size_t)(col0 + r) * ldb + c * 8;
    bDst = &lB[0][R0 * 32];
  }

  int offA[4];
  #pragma unroll
  for (int m = 0; m < 4; m++) {
    int r = wr * 64 + m * 16 + l15;
    offA[m] = r * 32 + (q ^ ((r >> 1) & 3)) * 8;
  }
  int offB[2];
  #pragma unroll
  for (int n = 0; n < 2; n++) {
    int r = wc * 32 + n * 16 + l15;
    offB[n] = r * 32 + (q ^ ((r >> 1) & 3)) * 8;
  }

  f32x4 acc[4][2];
  #pragma unroll
  for (int m = 0; m < 4; m++)
    #pragma unroll
    for (int n = 0; n < 2; n++) acc[m][n] = (f32x4){0.f, 0.f, 0.f, 0.f};

  const int iters = K >> 6;
  for (int it = 0; it < iters; it++) {
    #pragma unroll
    for (int j = 0; j < 2; j++) {
      async16(aSrc[j], aDst[j]);
      async16(aSrc[j] + 32, aDst[j] + halfA);
      aSrc[j] += 64;
    }
    async16(bSrc, bDst);
    async16(bSrc + 32, bDst + halfB);
    bSrc += 64;
    __syncthreads();
    #pragma unroll
    for (int h = 0; h < 2; h++) {
      bfx8 af[4];
      #pragma unroll
      for (int m = 0; m < 4; m++) af[m] = *(const bfx8*)&lA[h][offA[m]];
      bfx8 bf0 = *(const bfx8*)&lB[h][offB[0]];
      bfx8 bf1 = *(const bfx8*)&lB[h][offB[1]];
      #pragma unroll
      for (int m = 0; m < 4; m++) {
        acc[m][0] = __builtin_amdgcn_mfma_f32_16x16x32_bf16(af[m], bf0, acc[m][0], 0, 0, 0);
        acc[m][1] = __builtin_amdgcn_mfma_f32_16x16x32_bf16(af[m], bf1, acc[m][1], 0, 0, 0);
      }
    }
    __syncthreads();
  }

  #pragma unroll
  for (int m = 0; m < 4; m++) {
    #pragma unroll
    for (int n = 0; n < 2; n++) {
      int gr0 = row0 + wr * 64 + m * 16 + q * 4;
      int gc = col0 + wc * 32 + n * 16 + l15;
      #pragma unroll
      for (int i = 0; i < 4; i++) {
        int gr = gr0 + i;
        float v = acc[m][n][i];
        if (EPI == 0) {
          outF[(size_t)gr * ldout + gc] = v;
        } else if (EPI == 1) {
          float t = gelu_f(v + bias[gc]);
          outB[(size_t)gr * ldout + gc] = f2bfu(t);
        } else {
          outF[(size_t)gr * ldout + gc] = v + bias[gc] + add[(size_t)gr * ldadd + gc];
        }
      }
    }
  }
}

// ---------------- fused GRU GEMM + gates + slot-context ----------------
// THIS ROUND: counted-vmcnt software pipeline (T4). Each wave issues exactly
// 10 global_load_lds per K-tile (A:4, B:6). Schedule per tile pair:
//   STAGE(odd->buf1); vmcnt(10); bar; COMPUTE(buf0); lgkmcnt(0); bar;
//   STAGE(even->buf0); vmcnt(10); bar; COMPUTE(buf1); lgkmcnt(0); bar;
// vmcnt(10) waits only the CURRENT tile's 10 loads; the next tile's 10 stay
// in flight across the barrier (this is what R1's __syncthreads/vmcnt(0)
// destroyed). Post-compute lgkmcnt(0)+barrier fences buf reuse (all ds_reads
// complete before any wave's next STAGE overwrites). Static buffer names
// (no runtime LDS index — rule #20). Last tile peeled with vmcnt(0).
// Epilogue: Sf/alpha hoisted into regs (batch the latency), fast gates.
__global__ __launch_bounds__(256, 2) void gru_gemm(
    const unsigned short* __restrict__ Sb, const unsigned short* __restrict__ Whht,
    const float* __restrict__ alpha, const float* __restrict__ xw,
    const float* __restrict__ b_ih, const float* __restrict__ b_hh,
    const float* __restrict__ Sf, float* __restrict__ Snew,
    unsigned short* __restrict__ sc_b) {
  __shared__ __align__(16) unsigned short lA[2][2][128 * 32];   // [buf][half] 32 KB
  __shared__ __align__(16) unsigned short lB[2][2][192 * 32];   // [buf][half] 48 KB
  const int tid = threadIdx.x;
  const int wave = tid >> 6, lane = tid & 63;
  const int wr = wave >> 1, wc = wave & 1;
  const int q = lane >> 4, l15 = lane & 15;
  const int row0 = blockIdx.y * 128;
  const int col0 = blockIdx.x * 64;

  // ---- staging descriptors (loop-invariant; advance by 64 elems per STAGE) ----
  const int lr = lane >> 2, scn = lane & 3;
  const unsigned short* aSrc[2];
  int aOff[2];
  #pragma unroll
  for (int j = 0; j < 2; j++) {
    int R0 = (2 * wave + j) * 16;
    int r = R0 + lr;
    int c = scn ^ ((r >> 1) & 3);
    aSrc[j] = Sb + (size_t)(row0 + r) * DD + c * 8;
    aOff[j] = R0 * 32;
  }
  const unsigned short* bSrc[3];
  int bOff[3];
  #pragma unroll
  for (int j = 0; j < 3; j++) {
    int R0 = (3 * wave + j) * 16;
    int r = R0 + lr;
    int g = r >> 6, cr = r & 63;
    int c = scn ^ ((r >> 1) & 3);
    bSrc[j] = Whht + ((size_t)g * DD + col0 + cr) * DD + c * 8;
    bOff[j] = R0 * 32;
  }

  int offA[4];
  #pragma unroll
  for (int m = 0; m < 4; m++) {
    int r = wr * 64 + m * 16 + l15;
    offA[m] = r * 32 + (q ^ ((r >> 1) & 3)) * 8;
  }
  int offB[3][2];
  #pragma unroll
  for (int g = 0; g < 3; g++)
    #pragma unroll
    for (int n = 0; n < 2; n++) {
      int r = g * 64 + wc * 32 + n * 16 + l15;
      offB[g][n] = r * 32 + (q ^ ((r >> 1) & 3)) * 8;
    }

  f32x4 acc[3][4][2];
  #pragma unroll
  for (int g = 0; g < 3; g++)
    #pragma unroll
    for (int m = 0; m < 4; m++)
      #pragma unroll
      for (int n = 0; n < 2; n++) acc[g][m][n] = (f32x4){0.f, 0.f, 0.f, 0.f};

#define STAGE(BUF)                                                          \
  {                                                                         \
    _Pragma("unroll")                                                       \
    for (int j = 0; j < 2; j++) {                                           \
      async16(aSrc[j], &lA[BUF][0][aOff[j]]);                               \
      async16(aSrc[j] + 32, &lA[BUF][1][aOff[j]]);                          \
      aSrc[j] += 64;                                                        \
    }                                                                       \
    _Pragma("unroll")                                                       \
    for (int j = 0; j < 3; j++) {                                           \
      async16(bSrc[j], &lB[BUF][0][bOff[j]]);                               \
      async16(bSrc[j] + 32, &lB[BUF][1][bOff[j]]);                          \
      bSrc[j] += 64;                                                        \
    }                                                                       \
  }

#define COMPUTE(BUF)                                                        \
  {                                                                         \
    _Pragma("unroll")                                                       \
    for (int h = 0; h < 2; h++) {                                           \
      bfx8 af[4];                                                           \
      _Pragma("unroll")                                                     \
      for (int m = 0; m < 4; m++) af[m] = *(const bfx8*)&lA[BUF][h][offA[m]]; \
      _Pragma("unroll")                                                     \
      for (int g = 0; g < 3; g++) {                                         \
        bfx8 bf0 = *(const bfx8*)&lB[BUF][h][offB[g][0]];                   \
        bfx8 bf1 = *(const bfx8*)&lB[BUF][h][offB[g][1]];                   \
        _Pragma("unroll")                                                   \
        for (int m = 0; m < 4; m++) {                                       \
          acc[g][m][0] = __builtin_amdgcn_mfma_f32_16x16x32_bf16(af[m], bf0, acc[g][m][0], 0, 0, 0); \
          acc[g][m][1] = __builtin_amdgcn_mfma_f32_16x16x32_bf16(af[m], bf1, acc[g][m][1], 0, 0, 0); \
        }                                                                   \
      }                                                                     \
    }                                                                       \
  }

#define WAIT_VM10 asm volatile("s_waitcnt vmcnt(10)" ::: "memory")
#define WAIT_VM0  asm volatile("s_waitcnt vmcnt(0)" ::: "memory")
#define WAIT_LGKM asm volatile("s_waitcnt lgkmcnt(0)" ::: "memory")
#define BAR __builtin_amdgcn_s_barrier()

  // ---- pipelined K loop: 16 tiles of BK=64, processed as 8 pairs ----
  STAGE(0);                        // tile 0 -> buf0 (10 loads in flight)
  for (int t = 0; t < 8; t++) {
    STAGE(1);                      // tile 2t+1 -> buf1 (20 in flight)
    WAIT_VM10; BAR;                // tile 2t landed in buf0 (next stays in flight)
    COMPUTE(0);
    WAIT_LGKM; BAR;                // all reads of buf0 done -> safe to restage
    if (t < 7) {
      STAGE(0);                    // tile 2t+2 -> buf0
      WAIT_VM10;                   // tile 2t+1 landed in buf1
    } else {
      WAIT_VM0;                    // last tile: drain
    }
    BAR;
    COMPUTE(1);
    if (t < 7) { WAIT_LGKM; BAR; } // protect buf1 before next trip's STAGE(1)
  }

#undef STAGE
#undef COMPUTE
#undef WAIT_VM10
#undef WAIT_VM0
#undef WAIT_LGKM
#undef BAR

  // ---- epilogue: hoist Sf + alpha loads (batch latency), then gates ----
  float sfv[4][2][4];   // [m][n][i]
  float av[4][4];       // [m][i]
  #pragma unroll
  for (int m = 0; m < 4; m++) {
    #pragma unroll
    for (int i = 0; i < 4; i++) {
      int gr = row0 + wr * 64 + m * 16 + q * 4 + i;
      av[m][i] = alpha[gr];
      const float* sfr = Sf + (size_t)gr * DD;
      #pragma unroll
      for (int n = 0; n < 2; n++)
        sfv[m][n][i] = sfr[col0 + wc * 32 + n * 16 + l15];
    }
  }

  float scp[2][2] = {{0.f, 0.f}, {0.f, 0.f}};
  #pragma unroll
  for (int m = 0; m < 4; m++) {
    #pragma unroll
    for (int i = 0; i < 4; i++) {
      int gr = row0 + wr * 64 + m * 16 + q * 4 + i;
      float a = av[m][i];
      const float* xwr = xw + (size_t)(gr >> 5) * (3 * DD);
      float* orow = Snew + (size_t)gr * DD;
      #pragma unroll
      for (int n = 0; n < 2; n++) {
        int gc = col0 + wc * 32 + n * 16 + l15;
        float ghr = acc[0][m][n][i] + b_hh[gc];
        float ghz = acc[1][m][n][i] + b_hh[gc + DD];
        float ghn = acc[2][m][n][i] + b_hh[gc + 2 * DD];
        float r = sigm_fast(a * xwr[gc] + b_ih[gc] + ghr);
        float z = sigm_fast(a * xwr[gc + DD] + b_ih[gc + DD] + ghz);
        float nn = tanh_fast(a * xwr[gc + 2 * DD] + b_ih[gc + 2 * DD] + r * ghn);
        float sv = (1.0f - z) * nn + z * sfv[m][n][i];
        orow[gc] = sv;
        scp[m >> 1][n] += a * sv;
      }
    }
  }
  #pragma unroll
  for (int bh = 0; bh < 2; bh++)
    #pragma unroll
    for (int n = 0; n < 2; n++) {
      float v = scp[bh][n];
      v += __shfl_xor(v, 16);
      v += __shfl_xor(v, 32);
      if (q == 0) {
        int batch = (row0 >> 5) + wr * 2 + bh;
        int gc = col0 + wc * 32 + n * 16 + l15;
        sc_b[(size_t)batch * DD + gc] = f2bfu(v);
      }
    }
}

// ---------------- routing logits + softmax ----------------
__global__ __launch_bounds__(256) void route_softmax(
    const unsigned short* __restrict__ h_r, const float* __restrict__ w_r2,
    const float* __restrict__ b_r2, float* __restrict__ alpha_out) {
  int b = blockIdx.x;
  int n = threadIdx.x & 31, c = threadIdx.x >> 5;
  __shared__ float part[8][32];
  __shared__ float logits[32];
  const unsigned short* hr = h_r + (size_t)b * DD;
  float s = 0.f;
  for (int i = 0; i < 128; i++) {
    int k = c * 128 + i;
    s += bfu2f(hr[k]) * w_r2[k * NSLOT + n];
  }
  part[c][n] = s;
  __syncthreads();
  if (threadIdx.x < 32) {
    float t = b_r2[n];
    #pragma unroll
    for (int cc = 0; cc < 8; cc++) t += part[cc][n];
    logits[n] = t;
  }
  __syncthreads();
  if (threadIdx.x < 32) {
    float mx = -1e30f;
    #pragma unroll
    for (int j = 0; j < 32; j++) mx = fmaxf(mx, logits[j]);
    float den = 0.f;
    #pragma unroll
    for (int j = 0; j < 32; j++) den += expf(logits[j] - mx);
    alpha_out[(size_t)b * NSLOT + n] = expf(logits[n] - mx) / den;
  }
}

// ---------------- layernorm ----------------
template <int OUT_BF>
__global__ __launch_bounds__(256) void ln_k(const float* __restrict__ in,
                                            const float* __restrict__ gw,
                                            const float* __restrict__ bw,
                                            float* __restrict__ outF,
                                            unsigned short* __restrict__ outB) {
  int b = blockIdx.x;
  int tid = threadIdx.x;
  float4 v = ((const float4*)(in + (size_t)b * DD))[tid];
  float s = v.x + v.y + v.z + v.w;
  float s2 = v.x * v.x + v.y * v.y + v.z * v.z + v.w * v.w;
  #pragma unroll
  for (int o = 32; o > 0; o >>= 1) { s += __shfl_down(s, o); s2 += __shfl_down(s2, o); }
  __shared__ float as1[4], as2[4];
  int wave = tid >> 6, lane = tid & 63;
  if (lane == 0) { as1[wave] = s; as2[wave] = s2; }
  __syncthreads();
  float t1 = as1[0] + as1[1] + as1[2] + as1[3];
  float t2 = as2[0] + as2[1] + as2[2] + as2[3];
  float mu = t1 * (1.0f / DD);
  float var = t2 * (1.0f / DD) - mu * mu;
  float rstd = rsqrtf(var + 1e-5f);
  int d = tid * 4;
  float o0 = (v.x - mu) * rstd * gw[d] + bw[d];
  float o1 = (v.y - mu) * rstd * gw[d + 1] + bw[d + 1];
  float o2 = (v.z - mu) * rstd * gw[d + 2] + bw[d + 2];
  float o3 = (v.w - mu) * rstd * gw[d + 3] + bw[d + 3];
  if (OUT_BF) {
    ushort4 o; o.x = f2bfu(o0); o.y = f2bfu(o1); o.z = f2bfu(o2); o.w = f2bfu(o3);
    *(ushort4*)&outB[(size_t)b * DD + d] = o;
  } else {
    float4 o; o.x = o0; o.y = o1; o.z = o2; o.w = o3;
    *(float4*)&outF[(size_t)b * DD + d] = o;
  }
}

// ---------------- launch ----------------
extern "C" void kernel_launch(void* const* d_in, const int* in_sizes, int n_in,
                              void* d_out, int out_size, void* d_ws, size_t ws_size,
                              hipStream_t stream) {
  const float* x      = (const float*)d_in[0];
  const float* S      = (const float*)d_in[1];
  const float* w_r1   = (const float*)d_in[2];
  const float* b_r1   = (const float*)d_in[3];
  const float* w_r2   = (const float*)d_in[4];
  const float* b_r2   = (const float*)d_in[5];
  const float* w_ih   = (const float*)d_in[6];
  const float* w_hh   = (const float*)d_in[7];
  const float* b_ih   = (const float*)d_in[8];
  const float* b_hh   = (const float*)d_in[9];
  const float* w_proj = (const float*)d_in[10];
  const float* b_proj = (const float*)d_in[11];
  const float* ln1_g  = (const float*)d_in[12];
  const float* ln1_b  = (const float*)d_in[13];
  const float* w_f1   = (const float*)d_in[14];
  const float* b_f1   = (const float*)d_in[15];
  const float* w_f2   = (const float*)d_in[16];
  const float* b_f2   = (const float*)d_in[17];
  const float* ln2_g  = (const float*)d_in[18];
  const float* ln2_b  = (const float*)d_in[19];

  float* out_x = (float*)d_out;
  float* out_S = out_x + (size_t)BB * DD;
  float* out_a = out_S + (size_t)BB * NSLOT * DD;

  char* ws = (char*)d_ws;
  unsigned short* ctx    = (unsigned short*)(ws + 0);             // 4 MB [B][2D]
  unsigned short* w_r1t  = (unsigned short*)(ws + 4194304);       // 4 MB [D][2D]
  unsigned short* w_iht  = (unsigned short*)(ws + 8388608);       // 6 MB [3D][D]
  unsigned short* w_hht  = (unsigned short*)(ws + 14680064);      // 6 MB [3D][D]
  unsigned short* w_projt= (unsigned short*)(ws + 20971520);      // 2 MB [D][D]
  unsigned short* w_f1t  = (unsigned short*)(ws + 23068672);      // 8 MB [H][D]
  unsigned short* w_f2t  = (unsigned short*)(ws + 31457280);      // 8 MB [D][H]
  unsigned short* h_r    = (unsigned short*)(ws + 39845888);      // 2 MB [B][D]
  float*          xw     = (float*)(ws + 41943040);               // 12 MB [B][3D]
  unsigned short* Sb     = (unsigned short*)(ws + 54525952);      // 64 MB [B*NS][D]
  // aliases (lifetimes don't overlap originals):
  unsigned short* sc_b   = (unsigned short*)(ws + 0);             // reuse ctx (dead after xw GEMM)
  float*          x_mid  = (float*)(ws + 41943040);               // reuse xw (dead after gru)
  unsigned short* h_ln   = (unsigned short*)(ws + 46137344);      // xw + 4MB
  float*          pre2   = (float*)(ws + 48234496);               // xw + 6MB
  unsigned short* ff1    = (unsigned short*)(ws + 54525952);      // reuse Sb (dead after gru)

  dim3 blk(256);
  // --- prep: conversions + weight transposes ---
  cvt_x_ctx<<<1024, blk, 0, stream>>>(x, ctx);
  cvt4<<<32768, blk, 0, stream>>>(S, Sb, (BB * NSLOT * DD) / 4);
  slot_mean_k<<<4096, blk, 0, stream>>>(Sb, ctx);
  transp<<<dim3(32, 64), blk, 0, stream>>>(w_r1, w_r1t, 2 * DD, DD);
  transp<<<dim3(96, 32), blk, 0, stream>>>(w_ih, w_iht, DD, 3 * DD);
  transp<<<dim3(96, 32), blk, 0, stream>>>(w_hh, w_hht, DD, 3 * DD);
  transp<<<dim3(32, 32), blk, 0, stream>>>(w_proj, w_projt, DD, DD);
  transp<<<dim3(128, 32), blk, 0, stream>>>(w_f1, w_f1t, DD, HH);
  transp<<<dim3(32, 128), blk, 0, stream>>>(w_f2, w_f2t, HH, DD);

  // --- routing ---
  gemm_nt<1><<<dim3(16, 8), blk, 0, stream>>>(ctx, 2 * DD, w_r1t, 2 * DD, 2 * DD,
                                              b_r1, nullptr, 0, nullptr, h_r, DD);
  route_softmax<<<1024, blk, 0, stream>>>(h_r, w_r2, b_r2, out_a);

  // --- xw = x @ w_ih (rank-1 trick: gi = alpha * xw) ---
  gemm_nt<0><<<dim3(48, 8), blk, 0, stream>>>(ctx, 2 * DD, w_iht, DD, DD,
                                              nullptr, nullptr, 0, xw, nullptr, 3 * DD);

  // --- fused GRU: gh GEMM + gates + S_new + slot-context ---
  gru_gemm<<<dim3(16, 256), blk, 0, stream>>>(Sb, w_hht, out_a, xw, b_ih, b_hh, S,
                                              out_S, sc_b);

  // --- proj + residual ---
  gemm_nt<2><<<dim3(16, 8), blk, 0, stream>>>(sc_b, DD, w_projt, DD, DD,
                                              b_proj, x, DD, x_mid, nullptr, DD);

  // --- LN1 -> FFN -> LN2 ---
  ln_k<1><<<1024, blk, 0, stream>>>(x_mid, ln1_g, ln1_b, nullptr, h_ln);
  gemm_nt<1><<<dim3(64, 8), blk, 0, stream>>>(h_ln, DD, w_f1t, DD, DD,
                                              b_f1, nullptr, 0, nullptr, ff1, HH);
  gemm_nt<2><<<dim3(16, 8), blk, 0, stream>>>(ff1, HH, w_f2t, HH, HH,
                                              b_f2, x_mid, DD, pre2, nullptr, DD);
  ln_k<0><<<1024, blk, 0, stream>>>(pre2, ln2_g, ln2_b, out_x, nullptr);
}

// Round 5
// 752.631 us; speedup vs baseline: 1.3686x; 1.0091x over previous
//
#include <hip/hip_runtime.h>
#include <hip/hip_bf16.h>

#define BB 1024
#define NSLOT 32
#define DD 1024
#define HH 4096

typedef __bf16 bfx8 __attribute__((ext_vector_type(8)));
typedef float f32x4 __attribute__((ext_vector_type(4)));

__device__ __forceinline__ unsigned short f2bfu(float f) {
  union { float f; unsigned u; } v; v.f = f;
  unsigned r = v.u + 0x7fffu + ((v.u >> 16) & 1u);
  return (unsigned short)(r >> 16);
}
__device__ __forceinline__ float bfu2f(unsigned short u) {
  union { unsigned u; float f; } v; v.u = ((unsigned)u) << 16; return v.f;
}
__device__ __forceinline__ float gelu_f(float x) {
  return 0.5f * x * (1.0f + erff(x * 0.70710678118654752f));
}

// fast gate math: v_exp_f32 + v_rcp_f32 (~1 ulp each; error << bf16 rounding).
// Validated rounds 1-4 (absmax identical to libm version).
__device__ __forceinline__ float sigm_fast(float x) {
  return __builtin_amdgcn_rcpf(1.0f + __builtin_amdgcn_exp2f(-1.4426950408889634f * x));
}
__device__ __forceinline__ float tanh_fast(float x) {
  float t = __builtin_amdgcn_exp2f(2.8853900817779268f * x);
  return 1.0f - 2.0f * __builtin_amdgcn_rcpf(1.0f + t);
}

// async global->LDS, 16B per lane; LDS dest = wave-uniform base + lane*16
__device__ __forceinline__ void async16(const unsigned short* g, unsigned short* l) {
  __builtin_amdgcn_global_load_lds(
      (const __attribute__((address_space(1))) unsigned int*)g,
      (__attribute__((address_space(3))) unsigned int*)l, 16, 0, 0);
}

// ---------------- conversion / transpose kernels ----------------

__global__ __launch_bounds__(256) void cvt_x_ctx(const float* __restrict__ x,
                                                 unsigned short* __restrict__ ctx) {
  int i = blockIdx.x * 256 + threadIdx.x;
  int b = i >> 8;
  int c4 = (i & 255) * 4;
  float4 v = ((const float4*)(x + (size_t)b * DD))[i & 255];
  ushort4 o; o.x = f2bfu(v.x); o.y = f2bfu(v.y); o.z = f2bfu(v.z); o.w = f2bfu(v.w);
  *(ushort4*)&ctx[(size_t)b * (2 * DD) + c4] = o;
}

__global__ __launch_bounds__(256) void cvt4(const float* __restrict__ in,
                                            unsigned short* __restrict__ out, int n4) {
  int i = blockIdx.x * 256 + threadIdx.x;
  if (i >= n4) return;
  float4 v = ((const float4*)in)[i];
  ushort4 o; o.x = f2bfu(v.x); o.y = f2bfu(v.y); o.z = f2bfu(v.z); o.w = f2bfu(v.w);
  ((ushort4*)out)[i] = o;
}

__global__ __launch_bounds__(256) void slot_mean_k(const unsigned short* __restrict__ Sb,
                                                   unsigned short* __restrict__ ctx) {
  int i = blockIdx.x * 256 + threadIdx.x;
  int b = i >> 10, d = i & 1023;
  const unsigned short* p = Sb + (size_t)b * NSLOT * DD + d;
  float s = 0.f;
  #pragma unroll
  for (int sl = 0; sl < NSLOT; sl++) s += bfu2f(p[sl * DD]);
  ctx[(size_t)b * (2 * DD) + DD + d] = f2bfu(s * (1.0f / NSLOT));
}

__global__ __launch_bounds__(256) void transp(const float* __restrict__ in,
                                              unsigned short* __restrict__ out,
                                              int R, int C) {
  __shared__ float t[32][33];
  int tx = threadIdx.x & 31, ty = threadIdx.x >> 5;
  int c0 = blockIdx.x * 32, r0 = blockIdx.y * 32;
  #pragma unroll
  for (int i = 0; i < 4; i++) {
    int r = r0 + ty * 4 + i;
    t[ty * 4 + i][tx] = in[(size_t)r * C + c0 + tx];
  }
  __syncthreads();
  #pragma unroll
  for (int i = 0; i < 4; i++) {
    int c = c0 + ty * 4 + i;
    out[(size_t)c * R + r0 + tx] = f2bfu(t[tx][ty * 4 + i]);
  }
}

// ---------------- NT bf16 MFMA GEMM, counted-vmcnt pipelined ----------------
// THIS ROUND: port the pipeline proven on gru_gemm (R4: 425->272 us).
// Each wave issues exactly 6 global_load_lds per K-tile (A:4, B:2).
// Per tile pair: STAGE(1); vmcnt(6); bar; COMPUTE(0); lgkm; bar;
//                STAGE(0); vmcnt(6); bar; COMPUTE(1); lgkm; bar.
// Requires rows%128==0, cols%64==0, K%128==0 (tiles even) — all call sites ok.
template <int EPI>
__global__ __launch_bounds__(256) void gemm_nt(
    const unsigned short* __restrict__ A, int lda,
    const unsigned short* __restrict__ Bt, int ldb, int K,
    const float* __restrict__ bias,
    const float* __restrict__ add, int ldadd,
    float* __restrict__ outF, unsigned short* __restrict__ outB, int ldout) {
  __shared__ __align__(16) unsigned short lA[2][2][128 * 32];   // [buf][half] 32 KB
  __shared__ __align__(16) unsigned short lB[2][2][64 * 32];    // [buf][half] 16 KB
  const int tid = threadIdx.x;
  const int wave = tid >> 6, lane = tid & 63;
  const int wr = wave >> 1, wc = wave & 1;
  const int q = lane >> 4, l15 = lane & 15;
  const int row0 = blockIdx.y * 128;
  const int col0 = blockIdx.x * 64;

  const int lr = lane >> 2, scn = lane & 3;
  const unsigned short* aSrc[2];
  int aOff[2];
  #pragma unroll
  for (int j = 0; j < 2; j++) {
    int R0 = (2 * wave + j) * 16;
    int r = R0 + lr;
    int c = scn ^ ((r >> 1) & 3);
    aSrc[j] = A + (size_t)(row0 + r) * lda + c * 8;
    aOff[j] = R0 * 32;
  }
  const unsigned short* bSrc;
  int bOff0;
  {
    int R0 = wave * 16;
    int r = R0 + lr;
    int c = scn ^ ((r >> 1) & 3);
    bSrc = Bt + (size_t)(col0 + r) * ldb + c * 8;
    bOff0 = R0 * 32;
  }

  int offA[4];
  #pragma unroll
  for (int m = 0; m < 4; m++) {
    int r = wr * 64 + m * 16 + l15;
    offA[m] = r * 32 + (q ^ ((r >> 1) & 3)) * 8;
  }
  int offB[2];
  #pragma unroll
  for (int n = 0; n < 2; n++) {
    int r = wc * 32 + n * 16 + l15;
    offB[n] = r * 32 + (q ^ ((r >> 1) & 3)) * 8;
  }

  f32x4 acc[4][2];
  #pragma unroll
  for (int m = 0; m < 4; m++)
    #pragma unroll
    for (int n = 0; n < 2; n++) acc[m][n] = (f32x4){0.f, 0.f, 0.f, 0.f};

#define GSTAGE(BUF)                                                         \
  {                                                                         \
    _Pragma("unroll")                                                       \
    for (int j = 0; j < 2; j++) {                                           \
      async16(aSrc[j], &lA[BUF][0][aOff[j]]);                               \
      async16(aSrc[j] + 32, &lA[BUF][1][aOff[j]]);                          \
      aSrc[j] += 64;                                                        \
    }                                                                       \
    async16(bSrc, &lB[BUF][0][bOff0]);                                      \
    async16(bSrc + 32, &lB[BUF][1][bOff0]);                                 \
    bSrc += 64;                                                             \
  }

#define GCOMPUTE(BUF)                                                       \
  {                                                                         \
    _Pragma("unroll")                                                       \
    for (int h = 0; h < 2; h++) {                                           \
      bfx8 af[4];                                                           \
      _Pragma("unroll")                                                     \
      for (int m = 0; m < 4; m++) af[m] = *(const bfx8*)&lA[BUF][h][offA[m]]; \
      bfx8 bf0 = *(const bfx8*)&lB[BUF][h][offB[0]];                        \
      bfx8 bf1 = *(const bfx8*)&lB[BUF][h][offB[1]];                        \
      _Pragma("unroll")                                                     \
      for (int m = 0; m < 4; m++) {                                         \
        acc[m][0] = __builtin_amdgcn_mfma_f32_16x16x32_bf16(af[m], bf0, acc[m][0], 0, 0, 0); \
        acc[m][1] = __builtin_amdgcn_mfma_f32_16x16x32_bf16(af[m], bf1, acc[m][1], 0, 0, 0); \
      }                                                                     \
    }                                                                       \
  }

#define GWAIT_VM6 asm volatile("s_waitcnt vmcnt(6)" ::: "memory")
#define GWAIT_VM0 asm volatile("s_waitcnt vmcnt(0)" ::: "memory")
#define GWAIT_LGKM asm volatile("s_waitcnt lgkmcnt(0)" ::: "memory")
#define GBAR __builtin_amdgcn_s_barrier()

  const int pairs = K >> 7;   // tiles = K/64, pairs = tiles/2
  GSTAGE(0);
  for (int t = 0; t < pairs; t++) {
    GSTAGE(1);
    GWAIT_VM6; GBAR;
    GCOMPUTE(0);
    GWAIT_LGKM; GBAR;
    if (t < pairs - 1) {
      GSTAGE(0);
      GWAIT_VM6;
    } else {
      GWAIT_VM0;
    }
    GBAR;
    GCOMPUTE(1);
    if (t < pairs - 1) { GWAIT_LGKM; GBAR; }
  }

#undef GSTAGE
#undef GCOMPUTE
#undef GWAIT_VM6
#undef GWAIT_VM0
#undef GWAIT_LGKM
#undef GBAR

  #pragma unroll
  for (int m = 0; m < 4; m++) {
    #pragma unroll
    for (int n = 0; n < 2; n++) {
      int gr0 = row0 + wr * 64 + m * 16 + q * 4;
      int gc = col0 + wc * 32 + n * 16 + l15;
      #pragma unroll
      for (int i = 0; i < 4; i++) {
        int gr = gr0 + i;
        float v = acc[m][n][i];
        if (EPI == 0) {
          outF[(size_t)gr * ldout + gc] = v;
        } else if (EPI == 1) {
          float t = gelu_f(v + bias[gc]);
          outB[(size_t)gr * ldout + gc] = f2bfu(t);
        } else {
          outF[(size_t)gr * ldout + gc] = v + bias[gc] + add[(size_t)gr * ldadd + gc];
        }
      }
    }
  }
}

// ---------------- fused GRU GEMM + gates + slot-context ----------------
// (unchanged from R4 — measured 272 us, counted-vmcnt 2-deep pipeline)
__global__ __launch_bounds__(256, 2) void gru_gemm(
    const unsigned short* __restrict__ Sb, const unsigned short* __restrict__ Whht,
    const float* __restrict__ alpha, const float* __restrict__ xw,
    const float* __restrict__ b_ih, const float* __restrict__ b_hh,
    const float* __restrict__ Sf, float* __restrict__ Snew,
    unsigned short* __restrict__ sc_b) {
  __shared__ __align__(16) unsigned short lA[2][2][128 * 32];   // [buf][half] 32 KB
  __shared__ __align__(16) unsigned short lB[2][2][192 * 32];   // [buf][half] 48 KB
  const int tid = threadIdx.x;
  const int wave = tid >> 6, lane = tid & 63;
  const int wr = wave >> 1, wc = wave & 1;
  const int q = lane >> 4, l15 = lane & 15;
  const int row0 = blockIdx.y * 128;
  const int col0 = blockIdx.x * 64;

  const int lr = lane >> 2, scn = lane & 3;
  const unsigned short* aSrc[2];
  int aOff[2];
  #pragma unroll
  for (int j = 0; j < 2; j++) {
    int R0 = (2 * wave + j) * 16;
    int r = R0 + lr;
    int c = scn ^ ((r >> 1) & 3);
    aSrc[j] = Sb + (size_t)(row0 + r) * DD + c * 8;
    aOff[j] = R0 * 32;
  }
  const unsigned short* bSrc[3];
  int bOff[3];
  #pragma unroll
  for (int j = 0; j < 3; j++) {
    int R0 = (3 * wave + j) * 16;
    int r = R0 + lr;
    int g = r >> 6, cr = r & 63;
    int c = scn ^ ((r >> 1) & 3);
    bSrc[j] = Whht + ((size_t)g * DD + col0 + cr) * DD + c * 8;
    bOff[j] = R0 * 32;
  }

  int offA[4];
  #pragma unroll
  for (int m = 0; m < 4; m++) {
    int r = wr * 64 + m * 16 + l15;
    offA[m] = r * 32 + (q ^ ((r >> 1) & 3)) * 8;
  }
  int offB[3][2];
  #pragma unroll
  for (int g = 0; g < 3; g++)
    #pragma unroll
    for (int n = 0; n < 2; n++) {
      int r = g * 64 + wc * 32 + n * 16 + l15;
      offB[g][n] = r * 32 + (q ^ ((r >> 1) & 3)) * 8;
    }

  f32x4 acc[3][4][2];
  #pragma unroll
  for (int g = 0; g < 3; g++)
    #pragma unroll
    for (int m = 0; m < 4; m++)
      #pragma unroll
      for (int n = 0; n < 2; n++) acc[g][m][n] = (f32x4){0.f, 0.f, 0.f, 0.f};

#define STAGE(BUF)                                                          \
  {                                                                         \
    _Pragma("unroll")                                                       \
    for (int j = 0; j < 2; j++) {                                           \
      async16(aSrc[j], &lA[BUF][0][aOff[j]]);                               \
      async16(aSrc[j] + 32, &lA[BUF][1][aOff[j]]);                          \
      aSrc[j] += 64;                                                        \
    }                                                                       \
    _Pragma("unroll")                                                       \
    for (int j = 0; j < 3; j++) {                                           \
      async16(bSrc[j], &lB[BUF][0][bOff[j]]);                               \
      async16(bSrc[j] + 32, &lB[BUF][1][bOff[j]]);                          \
      bSrc[j] += 64;                                                        \
    }                                                                       \
  }

#define COMPUTE(BUF)                                                        \
  {                                                                         \
    _Pragma("unroll")                                                       \
    for (int h = 0; h < 2; h++) {                                           \
      bfx8 af[4];                                                           \
      _Pragma("unroll")                                                     \
      for (int m = 0; m < 4; m++) af[m] = *(const bfx8*)&lA[BUF][h][offA[m]]; \
      _Pragma("unroll")                                                     \
      for (int g = 0; g < 3; g++) {                                         \
        bfx8 bf0 = *(const bfx8*)&lB[BUF][h][offB[g][0]];                   \
        bfx8 bf1 = *(const bfx8*)&lB[BUF][h][offB[g][1]];                   \
        _Pragma("unroll")                                                   \
        for (int m = 0; m < 4; m++) {                                       \
          acc[g][m][0] = __builtin_amdgcn_mfma_f32_16x16x32_bf16(af[m], bf0, acc[g][m][0], 0, 0, 0); \
          acc[g][m][1] = __builtin_amdgcn_mfma_f32_16x16x32_bf16(af[m], bf1, acc[g][m][1], 0, 0, 0); \
        }                                                                   \
      }                                                                     \
    }                                                                       \
  }

#define WAIT_VM10 asm volatile("s_waitcnt vmcnt(10)" ::: "memory")
#define WAIT_VM0  asm volatile("s_waitcnt vmcnt(0)" ::: "memory")
#define WAIT_LGKM asm volatile("s_waitcnt lgkmcnt(0)" ::: "memory")
#define BAR __builtin_amdgcn_s_barrier()

  STAGE(0);
  for (int t = 0; t < 8; t++) {
    STAGE(1);
    WAIT_VM10; BAR;
    COMPUTE(0);
    WAIT_LGKM; BAR;
    if (t < 7) {
      STAGE(0);
      WAIT_VM10;
    } else {
      WAIT_VM0;
    }
    BAR;
    COMPUTE(1);
    if (t < 7) { WAIT_LGKM; BAR; }
  }

#undef STAGE
#undef COMPUTE
#undef WAIT_VM10
#undef WAIT_VM0
#undef WAIT_LGKM
#undef BAR

  // ---- epilogue: hoist Sf + alpha loads (batch latency), then gates ----
  float sfv[4][2][4];   // [m][n][i]
  float av[4][4];       // [m][i]
  #pragma unroll
  for (int m = 0; m < 4; m++) {
    #pragma unroll
    for (int i = 0; i < 4; i++) {
      int gr = row0 + wr * 64 + m * 16 + q * 4 + i;
      av[m][i] = alpha[gr];
      const float* sfr = Sf + (size_t)gr * DD;
      #pragma unroll
      for (int n = 0; n < 2; n++)
        sfv[m][n][i] = sfr[col0 + wc * 32 + n * 16 + l15];
    }
  }

  float scp[2][2] = {{0.f, 0.f}, {0.f, 0.f}};
  #pragma unroll
  for (int m = 0; m < 4; m++) {
    #pragma unroll
    for (int i = 0; i < 4; i++) {
      int gr = row0 + wr * 64 + m * 16 + q * 4 + i;
      float a = av[m][i];
      const float* xwr = xw + (size_t)(gr >> 5) * (3 * DD);
      float* orow = Snew + (size_t)gr * DD;
      #pragma unroll
      for (int n = 0; n < 2; n++) {
        int gc = col0 + wc * 32 + n * 16 + l15;
        float ghr = acc[0][m][n][i] + b_hh[gc];
        float ghz = acc[1][m][n][i] + b_hh[gc + DD];
        float ghn = acc[2][m][n][i] + b_hh[gc + 2 * DD];
        float r = sigm_fast(a * xwr[gc] + b_ih[gc] + ghr);
        float z = sigm_fast(a * xwr[gc + DD] + b_ih[gc + DD] + ghz);
        float nn = tanh_fast(a * xwr[gc + 2 * DD] + b_ih[gc + 2 * DD] + r * ghn);
        float sv = (1.0f - z) * nn + z * sfv[m][n][i];
        orow[gc] = sv;
        scp[m >> 1][n] += a * sv;
      }
    }
  }
  #pragma unroll
  for (int bh = 0; bh < 2; bh++)
    #pragma unroll
    for (int n = 0; n < 2; n++) {
      float v = scp[bh][n];
      v += __shfl_xor(v, 16);
      v += __shfl_xor(v, 32);
      if (q == 0) {
        int batch = (row0 >> 5) + wr * 2 + bh;
        int gc = col0 + wc * 32 + n * 16 + l15;
        sc_b[(size_t)batch * DD + gc] = f2bfu(v);
      }
    }
}

// ---------------- routing logits + softmax ----------------
__global__ __launch_bounds__(256) void route_softmax(
    const unsigned short* __restrict__ h_r, const float* __restrict__ w_r2,
    const float* __restrict__ b_r2, float* __restrict__ alpha_out) {
  int b = blockIdx.x;
  int n = threadIdx.x & 31, c = threadIdx.x >> 5;
  __shared__ float part[8][32];
  __shared__ float logits[32];
  const unsigned short* hr = h_r + (size_t)b * DD;
  float s = 0.f;
  for (int i = 0; i < 128; i++) {
    int k = c * 128 + i;
    s += bfu2f(hr[k]) * w_r2[k * NSLOT + n];
  }
  part[c][n] = s;
  __syncthreads();
  if (threadIdx.x < 32) {
    float t = b_r2[n];
    #pragma unroll
    for (int cc = 0; cc < 8; cc++) t += part[cc][n];
    logits[n] = t;
  }
  __syncthreads();
  if (threadIdx.x < 32) {
    float mx = -1e30f;
    #pragma unroll
    for (int j = 0; j < 32; j++) mx = fmaxf(mx, logits[j]);
    float den = 0.f;
    #pragma unroll
    for (int j = 0; j < 32; j++) den += expf(logits[j] - mx);
    alpha_out[(size_t)b * NSLOT + n] = expf(logits[n] - mx) / den;
  }
}

// ---------------- layernorm ----------------
template <int OUT_BF>
__global__ __launch_bounds__(256) void ln_k(const float* __restrict__ in,
                                            const float* __restrict__ gw,
                                            const float* __restrict__ bw,
                                            float* __restrict__ outF,
                                            unsigned short* __restrict__ outB) {
  int b = blockIdx.x;
  int tid = threadIdx.x;
  float4 v = ((const float4*)(in + (size_t)b * DD))[tid];
  float s = v.x + v.y + v.z + v.w;
  float s2 = v.x * v.x + v.y * v.y + v.z * v.z + v.w * v.w;
  #pragma unroll
  for (int o = 32; o > 0; o >>= 1) { s += __shfl_down(s, o); s2 += __shfl_down(s2, o); }
  __shared__ float as1[4], as2[4];
  int wave = tid >> 6, lane = tid & 63;
  if (lane == 0) { as1[wave] = s; as2[wave] = s2; }
  __syncthreads();
  float t1 = as1[0] + as1[1] + as1[2] + as1[3];
  float t2 = as2[0] + as2[1] + as2[2] + as2[3];
  float mu = t1 * (1.0f / DD);
  float var = t2 * (1.0f / DD) - mu * mu;
  float rstd = rsqrtf(var + 1e-5f);
  int d = tid * 4;
  float o0 = (v.x - mu) * rstd * gw[d] + bw[d];
  float o1 = (v.y - mu) * rstd * gw[d + 1] + bw[d + 1];
  float o2 = (v.z - mu) * rstd * gw[d + 2] + bw[d + 2];
  float o3 = (v.w - mu) * rstd * gw[d + 3] + bw[d + 3];
  if (OUT_BF) {
    ushort4 o; o.x = f2bfu(o0); o.y = f2bfu(o1); o.z = f2bfu(o2); o.w = f2bfu(o3);
    *(ushort4*)&outB[(size_t)b * DD + d] = o;
  } else {
    float4 o; o.x = o0; o.y = o1; o.z = o2; o.w = o3;
    *(float4*)&outF[(size_t)b * DD + d] = o;
  }
}

// ---------------- launch ----------------
extern "C" void kernel_launch(void* const* d_in, const int* in_sizes, int n_in,
                              void* d_out, int out_size, void* d_ws, size_t ws_size,
                              hipStream_t stream) {
  const float* x      = (const float*)d_in[0];
  const float* S      = (const float*)d_in[1];
  const float* w_r1   = (const float*)d_in[2];
  const float* b_r1   = (const float*)d_in[3];
  const float* w_r2   = (const float*)d_in[4];
  const float* b_r2   = (const float*)d_in[5];
  const float* w_ih   = (const float*)d_in[6];
  const float* w_hh   = (const float*)d_in[7];
  const float* b_ih   = (const float*)d_in[8];
  const float* b_hh   = (const float*)d_in[9];
  const float* w_proj = (const float*)d_in[10];
  const float* b_proj = (const float*)d_in[11];
  const float* ln1_g  = (const float*)d_in[12];
  const float* ln1_b  = (const float*)d_in[13];
  const float* w_f1   = (const float*)d_in[14];
  const float* b_f1   = (const float*)d_in[15];
  const float* w_f2   = (const float*)d_in[16];
  const float* b_f2   = (const float*)d_in[17];
  const float* ln2_g  = (const float*)d_in[18];
  const float* ln2_b  = (const float*)d_in[19];

  float* out_x = (float*)d_out;
  float* out_S = out_x + (size_t)BB * DD;
  float* out_a = out_S + (size_t)BB * NSLOT * DD;

  char* ws = (char*)d_ws;
  unsigned short* ctx    = (unsigned short*)(ws + 0);             // 4 MB [B][2D]
  unsigned short* w_r1t  = (unsigned short*)(ws + 4194304);       // 4 MB [D][2D]
  unsigned short* w_iht  = (unsigned short*)(ws + 8388608);       // 6 MB [3D][D]
  unsigned short* w_hht  = (unsigned short*)(ws + 14680064);      // 6 MB [3D][D]
  unsigned short* w_projt= (unsigned short*)(ws + 20971520);      // 2 MB [D][D]
  unsigned short* w_f1t  = (unsigned short*)(ws + 23068672);      // 8 MB [H][D]
  unsigned short* w_f2t  = (unsigned short*)(ws + 31457280);      // 8 MB [D][H]
  unsigned short* h_r    = (unsigned short*)(ws + 39845888);      // 2 MB [B][D]
  float*          xw     = (float*)(ws + 41943040);               // 12 MB [B][3D]
  unsigned short* Sb     = (unsigned short*)(ws + 54525952);      // 64 MB [B*NS][D]
  // aliases (lifetimes don't overlap originals):
  unsigned short* sc_b   = (unsigned short*)(ws + 0);             // reuse ctx (dead after xw GEMM)
  float*          x_mid  = (float*)(ws + 41943040);               // reuse xw (dead after gru)
  unsigned short* h_ln   = (unsigned short*)(ws + 46137344);      // xw + 4MB
  float*          pre2   = (float*)(ws + 48234496);               // xw + 6MB
  unsigned short* ff1    = (unsigned short*)(ws + 54525952);      // reuse Sb (dead after gru)

  dim3 blk(256);
  // --- prep: conversions + weight transposes ---
  cvt_x_ctx<<<1024, blk, 0, stream>>>(x, ctx);
  cvt4<<<32768, blk, 0, stream>>>(S, Sb, (BB * NSLOT * DD) / 4);
  slot_mean_k<<<4096, blk, 0, stream>>>(Sb, ctx);
  transp<<<dim3(32, 64), blk, 0, stream>>>(w_r1, w_r1t, 2 * DD, DD);
  transp<<<dim3(96, 32), blk, 0, stream>>>(w_ih, w_iht, DD, 3 * DD);
  transp<<<dim3(96, 32), blk, 0, stream>>>(w_hh, w_hht, DD, 3 * DD);
  transp<<<dim3(32, 32), blk, 0, stream>>>(w_proj, w_projt, DD, DD);
  transp<<<dim3(128, 32), blk, 0, stream>>>(w_f1, w_f1t, DD, HH);
  transp<<<dim3(32, 128), blk, 0, stream>>>(w_f2, w_f2t, HH, DD);

  // --- routing ---
  gemm_nt<1><<<dim3(16, 8), blk, 0, stream>>>(ctx, 2 * DD, w_r1t, 2 * DD, 2 * DD,
                                              b_r1, nullptr, 0, nullptr, h_r, DD);
  route_softmax<<<1024, blk, 0, stream>>>(h_r, w_r2, b_r2, out_a);

  // --- xw = x @ w_ih (rank-1 trick: gi = alpha * xw) ---
  gemm_nt<0><<<dim3(48, 8), blk, 0, stream>>>(ctx, 2 * DD, w_iht, DD, DD,
                                              nullptr, nullptr, 0, xw, nullptr, 3 * DD);

  // --- fused GRU: gh GEMM + gates + S_new + slot-context ---
  gru_gemm<<<dim3(16, 256), blk, 0, stream>>>(Sb, w_hht, out_a, xw, b_ih, b_hh, S,
                                              out_S, sc_b);

  // --- proj + residual ---
  gemm_nt<2><<<dim3(16, 8), blk, 0, stream>>>(sc_b, DD, w_projt, DD, DD,
                                              b_proj, x, DD, x_mid, nullptr, DD);

  // --- LN1 -> FFN -> LN2 ---
  ln_k<1><<<1024, blk, 0, stream>>>(x_mid, ln1_g, ln1_b, nullptr, h_ln);
  gemm_nt<1><<<dim3(64, 8), blk, 0, stream>>>(h_ln, DD, w_f1t, DD, DD,
                                              b_f1, nullptr, 0, nullptr, ff1, HH);
  gemm_nt<2><<<dim3(16, 8), blk, 0, stream>>>(ff1, HH, w_f2t, HH, HH,
                                              b_f2, x_mid, DD, pre2, nullptr, DD);
  ln_k<0><<<1024, blk, 0, stream>>>(pre2, ln2_g, ln2_b, out_x, nullptr);
}